// Round 1
// baseline (663.925 us; speedup 1.0000x reference)
//
#include <hip/hip_runtime.h>
#include <math.h>

// ---------------------------------------------------------------------------
// VisionEncoderMambaBlock  (B=4, L=4096, D=256, d_state=16, T=1024)
// Round 0: correctness-first fp32 pipeline with folded weights and a
// 2-pass chunked bidirectional selective scan. No materialized (b,l,d,n).
// ---------------------------------------------------------------------------

namespace {
constexpr int BB = 4;
constexpr int LL = 4096;
constexpr int DD = 256;
constexpr int NS = 16;       // d_state
constexpr int NCHUNK = 8;
constexpr int CHUNK = 512;   // LL / NCHUNK
constexpr int TOK = 1024;

constexpr size_t NROW = (size_t)BB * LL;   // 16384
constexpr size_t NE   = NROW * DD;         // 4,194,304
constexpr size_t NP   = (size_t)BB * TOK * DD; // 1,048,576
constexpr size_t NBC  = NROW * NS;         // 262,144
constexpr size_t NAGG = 2ull * BB * DD * NCHUNK * NS; // 262,144

// ws layout (float offsets). delta_f aliases xn (xn dead after gemm1).
constexpr size_t O_XN   = 0;
constexpr size_t O_DF   = O_XN;            // alias
constexpr size_t O_Z    = NE;
constexpr size_t O_H1   = 2 * NE;
constexpr size_t O_G2   = 3 * NE;
constexpr size_t O_DB   = 4 * NE;
constexpr size_t O_BMF  = 5 * NE;
constexpr size_t O_CMF  = O_BMF + NBC;
constexpr size_t O_BMB  = O_CMF + NBC;
constexpr size_t O_CMB  = O_BMB + NBC;
constexpr size_t O_SKIP = O_CMB + NBC;
constexpr size_t O_Y1   = O_SKIP + NP;
constexpr size_t O_Y2   = O_Y1 + NP;
constexpr size_t O_WF1  = O_Y2 + NP;           // 768*256
constexpr size_t O_BF1  = O_WF1 + 768 * 256;   // 768
constexpr size_t O_WF2F = O_BF1 + 768;         // 288*256
constexpr size_t O_B2F  = O_WF2F + 288 * 256;  // 288
constexpr size_t O_WF2B = O_B2F + 288;
constexpr size_t O_B2B  = O_WF2B + 288 * 256;
constexpr size_t O_APROD= O_B2B + 288;
constexpr size_t O_HEND = O_APROD + NAGG;
constexpr size_t O_HIN  = O_HEND + NAGG;
constexpr size_t O_MASK = O_HIN + NAGG;        // 1024
} // namespace

__device__ __forceinline__ float softplusf(float x) {
    return fmaxf(x, 0.f) + log1pf(__expf(-fabsf(x)));
}
__device__ __forceinline__ float siluf(float x) {
    return x / (1.f + __expf(-x));
}

// ---------------------------------------------------------------------------
// Weight prep: Wfused1 = [W1 ; Wcf@W2 ; Wcb@W2] (768x256), fused biases.
// grid (256 j, 2 mat) x 256 k
// ---------------------------------------------------------------------------
__global__ __launch_bounds__(256) void prep_wc_kernel(
    const float* __restrict__ W1, const float* __restrict__ b1,
    const float* __restrict__ W2, const float* __restrict__ b2,
    const float* __restrict__ Wcf, const float* __restrict__ bcf,
    const float* __restrict__ Wcb, const float* __restrict__ bcb,
    float* __restrict__ Wf1, float* __restrict__ bf1)
{
    int j = blockIdx.x, mat = blockIdx.y, k = threadIdx.x;
    const float* Wc = mat ? Wcb : Wcf;
    float acc = 0.f, accb = 0.f;
    for (int m = 0; m < 256; ++m) {
        float w = Wc[j * 256 + m];
        acc  = fmaf(w, W2[m * 256 + k], acc);
        accb = fmaf(w, b2[m], accb);
    }
    Wf1[(size_t)(256 + mat * 256 + j) * 256 + k] = acc;
    if (k == 0) bf1[256 + mat * 256 + j] = accb + (mat ? bcb[j] : bcf[j]);
    if (mat == 0) {
        Wf1[(size_t)j * 256 + k] = W1[j * 256 + k];
        if (k == 0) bf1[j] = b1[j];
    }
}

// ---------------------------------------------------------------------------
// Wf2 = [Wdt@Wdbc[:16] (256 rows) ; Wdbc[16:48] (32 rows)]  per direction.
// ---------------------------------------------------------------------------
__global__ __launch_bounds__(256) void prep_wdd_kernel(
    const float* __restrict__ Wdt_f, const float* __restrict__ Wdbc_f, const float* __restrict__ bdt_f,
    const float* __restrict__ Wdt_b, const float* __restrict__ Wdbc_b, const float* __restrict__ bdt_b,
    float* __restrict__ Wf2f, float* __restrict__ b2f,
    float* __restrict__ Wf2b, float* __restrict__ b2b)
{
    int j = blockIdx.x, mat = blockIdx.y, k = threadIdx.x;
    const float* Wdt  = mat ? Wdt_b : Wdt_f;
    const float* Wdbc = mat ? Wdbc_b : Wdbc_f;
    const float* bdt  = mat ? bdt_b : bdt_f;
    float* Wf2 = mat ? Wf2b : Wf2f;
    float* b2x = mat ? b2b : b2f;
    float acc = 0.f;
#pragma unroll
    for (int m = 0; m < 16; ++m)
        acc = fmaf(Wdt[j * 16 + m], Wdbc[m * 256 + k], acc);
    Wf2[(size_t)j * 256 + k] = acc;
    if (j < 32) Wf2[(size_t)(256 + j) * 256 + k] = Wdbc[(16 + j) * 256 + k];
    if (k == 0) { b2x[j] = bdt[j]; if (j < 32) b2x[256 + j] = 0.f; }
}

// ---------------------------------------------------------------------------
// Gaussian mask (closed over T=1024); one block of 1024 threads.
// ---------------------------------------------------------------------------
__global__ __launch_bounds__(1024) void mask_kernel(float* __restrict__ mask)
{
    __shared__ float red[16];
    __shared__ float bc;
    int t = threadIdx.x;
    const float c = 512.f; // (T+1)//2
    float ft = (float)t;
    float v = fabsf(ft - c);
    for (int o = 32; o > 0; o >>= 1) v += __shfl_xor(v, o, 64);
    if ((t & 63) == 0) red[t >> 6] = v;
    __syncthreads();
    if (t == 0) { float s = 0; for (int i = 0; i < 16; ++i) s += red[i]; bc = s * (1.f / 1024.f); }
    __syncthreads();
    float sigma = bc;
    float w = __expf(-0.5f * (ft - c) * (ft - c) / (sigma * sigma));
    v = w;
    for (int o = 32; o > 0; o >>= 1) v += __shfl_xor(v, o, 64);
    if ((t & 63) == 0) red[t >> 6] = v;
    __syncthreads();
    if (t == 0) { float s = 0; for (int i = 0; i < 16; ++i) s += red[i]; bc = s; }
    __syncthreads();
    mask[t] = w / bc;
}

// ---------------------------------------------------------------------------
// LayerNorm + skip adapool. One block = 4 consecutive rows (one pool group).
// ---------------------------------------------------------------------------
__global__ __launch_bounds__(256) void ln_kernel(
    const float* __restrict__ x, const float* __restrict__ lng, const float* __restrict__ lnb,
    float* __restrict__ xn, float* __restrict__ skipo)
{
    __shared__ float red[8];
    __shared__ float mv[2];
    int t = threadIdx.x;
    int r0 = blockIdx.x * 4;
    float gg = lng[t], bbv = lnb[t];
    float acc = 0.f;
    for (int i = 0; i < 4; ++i) {
        size_t r = r0 + i;
        float v = x[r * 256 + t];
        float s = v, q = v * v;
        for (int o = 32; o > 0; o >>= 1) { s += __shfl_xor(s, o, 64); q += __shfl_xor(q, o, 64); }
        if ((t & 63) == 0) { red[t >> 6] = s; red[4 + (t >> 6)] = q; }
        __syncthreads();
        if (t == 0) {
            float S = red[0] + red[1] + red[2] + red[3];
            float Q = red[4] + red[5] + red[6] + red[7];
            float mu = S * (1.f / 256.f);
            mv[0] = mu;
            mv[1] = rsqrtf(Q * (1.f / 256.f) - mu * mu + 1e-5f);
        }
        __syncthreads();
        xn[r * 256 + t] = (v - mv[0]) * mv[1] * gg + bbv;
        acc += v;
        __syncthreads();
    }
    int b = r0 >> 12;
    int g = (r0 & 4095) >> 2;
    skipo[((size_t)b * TOK + g) * 256 + t] = acc * 0.25f;
}

// ---------------------------------------------------------------------------
// GEMM1: C[16384 x 768] = xn @ Wf1^T + bf1; route to z / softplus->h1 / ->g2.
// 64x64 tile, BK=16, 256 threads, 4x4 per thread.
// ---------------------------------------------------------------------------
__global__ __launch_bounds__(256) void gemm1_kernel(
    const float* __restrict__ A, const float* __restrict__ Bw, const float* __restrict__ bias,
    float* __restrict__ z, float* __restrict__ h1, float* __restrict__ g2)
{
    __shared__ __align__(16) float As[16][68];
    __shared__ __align__(16) float Bs[16][68];
    int tid = threadIdx.x;
    int m0 = blockIdx.x * 64;
    int j0 = blockIdx.y * 64;
    int lm = tid >> 2, kq = (tid & 3) * 4;
    int tx = tid & 15, ty = tid >> 4;
    float acc[4][4] = {};
    for (int k0 = 0; k0 < 256; k0 += 16) {
        float4 av = *(const float4*)&A[((size_t)(m0 + lm)) * 256 + k0 + kq];
        float4 bv = *(const float4*)&Bw[((size_t)(j0 + lm)) * 256 + k0 + kq];
        __syncthreads();
        As[kq + 0][lm] = av.x; As[kq + 1][lm] = av.y; As[kq + 2][lm] = av.z; As[kq + 3][lm] = av.w;
        Bs[kq + 0][lm] = bv.x; Bs[kq + 1][lm] = bv.y; Bs[kq + 2][lm] = bv.z; Bs[kq + 3][lm] = bv.w;
        __syncthreads();
#pragma unroll
        for (int kk = 0; kk < 16; ++kk) {
            float4 a4 = *(const float4*)&As[kk][ty * 4];
            float4 b4 = *(const float4*)&Bs[kk][tx * 4];
            float aa[4] = {a4.x, a4.y, a4.z, a4.w};
            float bb[4] = {b4.x, b4.y, b4.z, b4.w};
#pragma unroll
            for (int i = 0; i < 4; ++i)
#pragma unroll
                for (int jj = 0; jj < 4; ++jj)
                    acc[i][jj] = fmaf(aa[i], bb[jj], acc[i][jj]);
        }
    }
    int target = j0 >> 8;               // 0:z  1:h1  2:g2
    int jl = (j0 & 255) + tx * 4;
    float* outp = (target == 0) ? z : (target == 1 ? h1 : g2);
    bool actv = (target != 0);
    float bsv[4];
#pragma unroll
    for (int jj = 0; jj < 4; ++jj) bsv[jj] = bias[j0 + tx * 4 + jj];
#pragma unroll
    for (int i = 0; i < 4; ++i) {
        size_t r = m0 + ty * 4 + i;
        float vv[4];
#pragma unroll
        for (int jj = 0; jj < 4; ++jj) {
            float v = acc[i][jj] + bsv[jj];
            vv[jj] = actv ? softplusf(v) : v;
        }
        float4 o; o.x = vv[0]; o.y = vv[1]; o.z = vv[2]; o.w = vv[3];
        *(float4*)&outp[r * 256 + jl] = o;
    }
}

// ---------------------------------------------------------------------------
// GEMM2 (per dir): [delta_pre | Bm | Cm] = h @ Wf2^T + b2.  N=288 (5 tiles).
// ---------------------------------------------------------------------------
__global__ __launch_bounds__(256) void gemm2_kernel(
    const float* __restrict__ h1, const float* __restrict__ g2,
    const float* __restrict__ Wf, const float* __restrict__ bf2,
    const float* __restrict__ Wb, const float* __restrict__ bb2,
    float* __restrict__ dlf, float* __restrict__ dlb,
    float* __restrict__ BmF, float* __restrict__ CmF,
    float* __restrict__ BmB, float* __restrict__ CmB)
{
    __shared__ __align__(16) float As[16][68];
    __shared__ __align__(16) float Bs[16][68];
    int tid = threadIdx.x;
    int m0 = blockIdx.x * 64;
    int j0 = blockIdx.y * 64;
    int dir = blockIdx.z;
    const float* A    = dir ? g2 : h1;
    const float* Bw   = dir ? Wb : Wf;
    const float* bias = dir ? bb2 : bf2;
    float* dl = dir ? dlb : dlf;
    float* Bm = dir ? BmB : BmF;
    float* Cm = dir ? CmB : CmF;
    int lm = tid >> 2, kq = (tid & 3) * 4;
    int tx = tid & 15, ty = tid >> 4;
    int jr = j0 + lm;
    float acc[4][4] = {};
    for (int k0 = 0; k0 < 256; k0 += 16) {
        float4 av = *(const float4*)&A[((size_t)(m0 + lm)) * 256 + k0 + kq];
        float4 bv = make_float4(0.f, 0.f, 0.f, 0.f);
        if (jr < 288) bv = *(const float4*)&Bw[((size_t)jr) * 256 + k0 + kq];
        __syncthreads();
        As[kq + 0][lm] = av.x; As[kq + 1][lm] = av.y; As[kq + 2][lm] = av.z; As[kq + 3][lm] = av.w;
        Bs[kq + 0][lm] = bv.x; Bs[kq + 1][lm] = bv.y; Bs[kq + 2][lm] = bv.z; Bs[kq + 3][lm] = bv.w;
        __syncthreads();
#pragma unroll
        for (int kk = 0; kk < 16; ++kk) {
            float4 a4 = *(const float4*)&As[kk][ty * 4];
            float4 b4 = *(const float4*)&Bs[kk][tx * 4];
            float aa[4] = {a4.x, a4.y, a4.z, a4.w};
            float bb[4] = {b4.x, b4.y, b4.z, b4.w};
#pragma unroll
            for (int i = 0; i < 4; ++i)
#pragma unroll
                for (int jj = 0; jj < 4; ++jj)
                    acc[i][jj] = fmaf(aa[i], bb[jj], acc[i][jj]);
        }
    }
#pragma unroll
    for (int i = 0; i < 4; ++i) {
        size_t r = m0 + ty * 4 + i;
#pragma unroll
        for (int jj = 0; jj < 4; ++jj) {
            int jg = j0 + tx * 4 + jj;
            if (jg >= 288) continue;
            float v = acc[i][jj] + bias[jg];
            if (jg < 256)      dl[r * 256 + jg] = softplusf(v);
            else if (jg < 272) Bm[r * 16 + (jg - 256)] = v;
            else               Cm[r * 16 + (jg - 272)] = v;
        }
    }
}

// ---------------------------------------------------------------------------
// Scan pass 1: per (dir,b,d,n,chunk) compute chunk aggregate (aprod, hend).
// n = lane&15 (16 d per block). dir=1 iterates descending t.
// ---------------------------------------------------------------------------
__global__ __launch_bounds__(256) void scan1_kernel(
    const float* __restrict__ df, const float* __restrict__ db,
    const float* __restrict__ xf, const float* __restrict__ xb,
    const float* __restrict__ bmf, const float* __restrict__ bmb,
    const float* __restrict__ alogf, const float* __restrict__ alogb,
    float* __restrict__ aprod, float* __restrict__ hend)
{
    int tid = threadIdx.x;
    int n = tid & 15;
    int dlo = (tid >> 4) & 15;
    int bx = blockIdx.x;
    int dhi = bx & 15;
    int c = (bx >> 4) & 7;
    int b = bx >> 7;
    int dir = blockIdx.y;
    int d = dhi * 16 + dlo;
    const float* delta = dir ? db : df;
    const float* xin   = dir ? xb : xf;
    const float* Bm    = dir ? bmb : bmf;
    const float* Alog  = dir ? alogb : alogf;
    float A_dn = -__expf(Alog[d * 16 + n]);
    int base = c * CHUNK;
    float h = 0.f, sd = 0.f;
#pragma unroll 4
    for (int it = 0; it < CHUNK; ++it) {
        int t = dir ? (base + CHUNK - 1 - it) : (base + it);
        size_t row = (size_t)b * LL + t;
        float dlt = delta[row * DD + d];
        float xv  = xin[row * DD + d];
        float Bv  = Bm[row * NS + n];
        float a = __expf(dlt * A_dn);
        h = fmaf(a, h, dlt * Bv * xv);
        sd += dlt;
    }
    size_t idx = ((((size_t)dir * BB + b) * DD + d) * NCHUNK + c) * NS + n;
    aprod[idx] = __expf(sd * A_dn);
    hend[idx] = h;
}

// ---------------------------------------------------------------------------
// Scan pass 2: chain the 8 chunk aggregates -> entering state per chunk.
// ---------------------------------------------------------------------------
__global__ __launch_bounds__(256) void scan2_kernel(
    const float* __restrict__ aprod, const float* __restrict__ hend, float* __restrict__ hin)
{
    int g = blockIdx.x * 256 + threadIdx.x;
    int n = g & 15, d = (g >> 4) & 255, b = (g >> 12) & 3, dir = (g >> 14) & 1;
    size_t bidx = (((size_t)dir * BB + b) * DD + d) * NCHUNK;
    float s = 0.f;
    if (!dir) {
        for (int c = 0; c < NCHUNK; ++c) {
            size_t idx = (bidx + c) * NS + n;
            hin[idx] = s;
            s = fmaf(aprod[idx], s, hend[idx]);
        }
    } else {
        for (int c = NCHUNK - 1; c >= 0; --c) {
            size_t idx = (bidx + c) * NS + n;
            hin[idx] = s;
            s = fmaf(aprod[idx], s, hend[idx]);
        }
    }
}

// ---------------------------------------------------------------------------
// Scan pass 3: replay chunk with true prefix, contract with Cm over n
// (shfl_xor over 16 lanes), add D*x, accumulate adapool groups of 4, write
// pooled y (b, g, d). Never materializes full y.
// ---------------------------------------------------------------------------
__global__ __launch_bounds__(256) void scan3_kernel(
    const float* __restrict__ df, const float* __restrict__ db,
    const float* __restrict__ xf, const float* __restrict__ xb,
    const float* __restrict__ bmf, const float* __restrict__ bmb,
    const float* __restrict__ cmf, const float* __restrict__ cmb,
    const float* __restrict__ alogf, const float* __restrict__ alogb,
    const float* __restrict__ Dfp, const float* __restrict__ Dbp,
    const float* __restrict__ hin,
    float* __restrict__ y1, float* __restrict__ y2)
{
    int tid = threadIdx.x;
    int n = tid & 15;
    int dlo = (tid >> 4) & 15;
    int bx = blockIdx.x;
    int dhi = bx & 15;
    int c = (bx >> 4) & 7;
    int b = bx >> 7;
    int dir = blockIdx.y;
    int d = dhi * 16 + dlo;
    const float* delta = dir ? db : df;
    const float* xin   = dir ? xb : xf;
    const float* Bm    = dir ? bmb : bmf;
    const float* Cm    = dir ? cmb : cmf;
    const float* Alog  = dir ? alogb : alogf;
    const float* Dv    = dir ? Dbp : Dfp;
    float* yout = dir ? y2 : y1;
    float A_dn = -__expf(Alog[d * 16 + n]);
    float Dd = Dv[d];
    size_t idx = ((((size_t)dir * BB + b) * DD + d) * NCHUNK + c) * NS + n;
    float h = hin[idx];
    int base = c * CHUNK;
    float pool = 0.f;
    for (int it = 0; it < CHUNK; ++it) {
        int t = dir ? (base + CHUNK - 1 - it) : (base + it);
        size_t row = (size_t)b * LL + t;
        float dlt = delta[row * DD + d];
        float xv  = xin[row * DD + d];
        float Bv  = Bm[row * NS + n];
        float Cv  = Cm[row * NS + n];
        float a = __expf(dlt * A_dn);
        h = fmaf(a, h, dlt * Bv * xv);
        float yc = h * Cv;
        yc += __shfl_xor(yc, 1, 64);
        yc += __shfl_xor(yc, 2, 64);
        yc += __shfl_xor(yc, 4, 64);
        yc += __shfl_xor(yc, 8, 64);
        pool += yc + Dd * xv;
        bool gend = dir ? ((t & 3) == 0) : ((t & 3) == 3);
        if (gend) {
            if (n == 0)
                yout[((size_t)b * TOK + (t >> 2)) * DD + d] = pool * 0.25f;
            pool = 0.f;
        }
    }
}

// ---------------------------------------------------------------------------
// Final: zp = silu(pool(z)); out = zp*(silu(y1*mask)+silu(y2*mask)) + skip
// ---------------------------------------------------------------------------
__global__ __launch_bounds__(256) void final_kernel(
    const float* __restrict__ z, const float* __restrict__ y1, const float* __restrict__ y2,
    const float* __restrict__ mask, const float* __restrict__ skipi, float* __restrict__ out)
{
    int p = blockIdx.x;
    int b = p >> 10, g = p & 1023;
    int d = threadIdx.x;
    size_t zr = ((size_t)b * LL + (size_t)g * 4) * DD + d;
    float zs = z[zr] + z[zr + 256] + z[zr + 512] + z[zr + 768];
    float zp = siluf(0.25f * zs);
    size_t ip = ((size_t)b * TOK + g) * DD + d;
    float mk = mask[g];
    float a1 = y1[ip] * mk, a2 = y2[ip] * mk;
    out[ip] = zp * (siluf(a1) + siluf(a2)) + skipi[ip];
}

// ---------------------------------------------------------------------------
extern "C" void kernel_launch(void* const* d_in, const int* in_sizes, int n_in,
                              void* d_out, int out_size, void* d_ws, size_t ws_size,
                              hipStream_t stream)
{
    const float* x      = (const float*)d_in[0];
    const float* ln_g   = (const float*)d_in[1];
    const float* ln_b   = (const float*)d_in[2];
    const float* W1     = (const float*)d_in[3];
    const float* b1     = (const float*)d_in[4];
    const float* W2     = (const float*)d_in[5];
    const float* b2     = (const float*)d_in[6];
    const float* Wcf    = (const float*)d_in[7];
    const float* bcf    = (const float*)d_in[8];
    const float* Wcb    = (const float*)d_in[9];
    const float* bcb    = (const float*)d_in[10];
    const float* Wdbc_f = (const float*)d_in[11];
    const float* Wdt_f  = (const float*)d_in[12];
    const float* bdt_f  = (const float*)d_in[13];
    const float* Alog_f = (const float*)d_in[14];
    const float* D_f    = (const float*)d_in[15];
    const float* Wdbc_b = (const float*)d_in[16];
    const float* Wdt_b  = (const float*)d_in[17];
    const float* bdt_b  = (const float*)d_in[18];
    const float* Alog_b = (const float*)d_in[19];
    const float* D_b    = (const float*)d_in[20];
    float* out = (float*)d_out;
    float* ws  = (float*)d_ws;

    float* xn   = ws + O_XN;
    float* zb   = ws + O_Z;
    float* h1b  = ws + O_H1;
    float* g2b  = ws + O_G2;
    float* dfb  = ws + O_DF;   // aliases xn (dead after gemm1)
    float* dbb  = ws + O_DB;
    float* bmf  = ws + O_BMF;
    float* cmf  = ws + O_CMF;
    float* bmb  = ws + O_BMB;
    float* cmb  = ws + O_CMB;
    float* skb  = ws + O_SKIP;
    float* y1b  = ws + O_Y1;
    float* y2b  = ws + O_Y2;
    float* wf1  = ws + O_WF1;
    float* bf1  = ws + O_BF1;
    float* wf2f = ws + O_WF2F;
    float* b2f  = ws + O_B2F;
    float* wf2b = ws + O_WF2B;
    float* b2b  = ws + O_B2B;
    float* apr  = ws + O_APROD;
    float* hnd  = ws + O_HEND;
    float* hin  = ws + O_HIN;
    float* mkb  = ws + O_MASK;

    prep_wc_kernel<<<dim3(256, 2), 256, 0, stream>>>(W1, b1, W2, b2, Wcf, bcf, Wcb, bcb, wf1, bf1);
    prep_wdd_kernel<<<dim3(256, 2), 256, 0, stream>>>(Wdt_f, Wdbc_f, bdt_f, Wdt_b, Wdbc_b, bdt_b,
                                                      wf2f, b2f, wf2b, b2b);
    mask_kernel<<<1, 1024, 0, stream>>>(mkb);
    ln_kernel<<<4096, 256, 0, stream>>>(x, ln_g, ln_b, xn, skb);
    gemm1_kernel<<<dim3(256, 12), 256, 0, stream>>>(xn, wf1, bf1, zb, h1b, g2b);
    gemm2_kernel<<<dim3(256, 5, 2), 256, 0, stream>>>(h1b, g2b, wf2f, b2f, wf2b, b2b,
                                                      dfb, dbb, bmf, cmf, bmb, cmb);
    scan1_kernel<<<dim3(512, 2), 256, 0, stream>>>(dfb, dbb, h1b, g2b, bmf, bmb,
                                                   Alog_f, Alog_b, apr, hnd);
    scan2_kernel<<<128, 256, 0, stream>>>(apr, hnd, hin);
    scan3_kernel<<<dim3(512, 2), 256, 0, stream>>>(dfb, dbb, h1b, g2b, bmf, bmb, cmf, cmb,
                                                   Alog_f, Alog_b, D_f, D_b, hin, y1b, y2b);
    final_kernel<<<4096, 256, 0, stream>>>(zb, y1b, y2b, mkb, skb, out);
}

// Round 2
// 429.331 us; speedup vs baseline: 1.5464x; 1.5464x over previous
//
#include <hip/hip_runtime.h>
#include <math.h>

// ---------------------------------------------------------------------------
// VisionEncoderMambaBlock  (B=4, L=4096, D=256, d_state=16, T=1024)
// Round 1: scan redesign — one thread per d, all 16 n in registers.
//   - coalesced delta/x loads (lane == d), loaded once per (t,d)
//   - B/C rows are wave-uniform broadcast float4 loads
//   - n-contraction in-register (no shfl/DS ops)
//   - 64 chunks of 64 t; pass-2 prefix computed in place over hend
// ---------------------------------------------------------------------------

namespace {
constexpr int BB = 4;
constexpr int LL = 4096;
constexpr int DD = 256;
constexpr int NS = 16;       // d_state
constexpr int NCH = 64;
constexpr int CLEN = 64;     // LL / NCH
constexpr int TOK = 1024;

constexpr size_t NROW = (size_t)BB * LL;   // 16384
constexpr size_t NE   = NROW * DD;         // 4,194,304
constexpr size_t NP   = (size_t)BB * TOK * DD; // 1,048,576
constexpr size_t NBC  = NROW * NS;         // 262,144
constexpr size_t NAGG = 2ull * BB * DD * NCH * NS; // 4,194,304

// ws layout (float offsets). delta_f aliases xn (xn dead after gemm1).
constexpr size_t O_XN   = 0;
constexpr size_t O_DF   = O_XN;            // alias
constexpr size_t O_Z    = NE;
constexpr size_t O_H1   = 2 * NE;
constexpr size_t O_G2   = 3 * NE;
constexpr size_t O_DB   = 4 * NE;
constexpr size_t O_BMF  = 5 * NE;
constexpr size_t O_CMF  = O_BMF + NBC;
constexpr size_t O_BMB  = O_CMF + NBC;
constexpr size_t O_CMB  = O_BMB + NBC;
constexpr size_t O_SKIP = O_CMB + NBC;
constexpr size_t O_Y1   = O_SKIP + NP;
constexpr size_t O_Y2   = O_Y1 + NP;
constexpr size_t O_WF1  = O_Y2 + NP;           // 768*256
constexpr size_t O_BF1  = O_WF1 + 768 * 256;   // 768
constexpr size_t O_WF2F = O_BF1 + 768;         // 288*256
constexpr size_t O_B2F  = O_WF2F + 288 * 256;  // 288
constexpr size_t O_WF2B = O_B2F + 288;
constexpr size_t O_B2B  = O_WF2B + 288 * 256;
constexpr size_t O_APROD= O_B2B + 288;
constexpr size_t O_HEND = O_APROD + NAGG;      // becomes hin in place (scan2)
constexpr size_t O_MASK = O_HEND + NAGG;       // 1024
} // namespace

__device__ __forceinline__ float softplusf(float x) {
    return fmaxf(x, 0.f) + log1pf(__expf(-fabsf(x)));
}
__device__ __forceinline__ float siluf(float x) {
    return x / (1.f + __expf(-x));
}

// ---------------------------------------------------------------------------
// Weight prep: Wfused1 = [W1 ; Wcf@W2 ; Wcb@W2] (768x256), fused biases.
// ---------------------------------------------------------------------------
__global__ __launch_bounds__(256) void prep_wc_kernel(
    const float* __restrict__ W1, const float* __restrict__ b1,
    const float* __restrict__ W2, const float* __restrict__ b2,
    const float* __restrict__ Wcf, const float* __restrict__ bcf,
    const float* __restrict__ Wcb, const float* __restrict__ bcb,
    float* __restrict__ Wf1, float* __restrict__ bf1)
{
    int j = blockIdx.x, mat = blockIdx.y, k = threadIdx.x;
    const float* Wc = mat ? Wcb : Wcf;
    float acc = 0.f, accb = 0.f;
    for (int m = 0; m < 256; ++m) {
        float w = Wc[j * 256 + m];
        acc  = fmaf(w, W2[m * 256 + k], acc);
        accb = fmaf(w, b2[m], accb);
    }
    Wf1[(size_t)(256 + mat * 256 + j) * 256 + k] = acc;
    if (k == 0) bf1[256 + mat * 256 + j] = accb + (mat ? bcb[j] : bcf[j]);
    if (mat == 0) {
        Wf1[(size_t)j * 256 + k] = W1[j * 256 + k];
        if (k == 0) bf1[j] = b1[j];
    }
}

// ---------------------------------------------------------------------------
// Wf2 = [Wdt@Wdbc[:16] (256 rows) ; Wdbc[16:48] (32 rows)]  per direction.
// ---------------------------------------------------------------------------
__global__ __launch_bounds__(256) void prep_wdd_kernel(
    const float* __restrict__ Wdt_f, const float* __restrict__ Wdbc_f, const float* __restrict__ bdt_f,
    const float* __restrict__ Wdt_b, const float* __restrict__ Wdbc_b, const float* __restrict__ bdt_b,
    float* __restrict__ Wf2f, float* __restrict__ b2f,
    float* __restrict__ Wf2b, float* __restrict__ b2b)
{
    int j = blockIdx.x, mat = blockIdx.y, k = threadIdx.x;
    const float* Wdt  = mat ? Wdt_b : Wdt_f;
    const float* Wdbc = mat ? Wdbc_b : Wdbc_f;
    const float* bdt  = mat ? bdt_b : bdt_f;
    float* Wf2 = mat ? Wf2b : Wf2f;
    float* b2x = mat ? b2b : b2f;
    float acc = 0.f;
#pragma unroll
    for (int m = 0; m < 16; ++m)
        acc = fmaf(Wdt[j * 16 + m], Wdbc[m * 256 + k], acc);
    Wf2[(size_t)j * 256 + k] = acc;
    if (j < 32) Wf2[(size_t)(256 + j) * 256 + k] = Wdbc[(16 + j) * 256 + k];
    if (k == 0) { b2x[j] = bdt[j]; if (j < 32) b2x[256 + j] = 0.f; }
}

// ---------------------------------------------------------------------------
// Gaussian mask (closed over T=1024); one block of 1024 threads.
// ---------------------------------------------------------------------------
__global__ __launch_bounds__(1024) void mask_kernel(float* __restrict__ mask)
{
    __shared__ float red[16];
    __shared__ float bc;
    int t = threadIdx.x;
    const float c = 512.f; // (T+1)//2
    float ft = (float)t;
    float v = fabsf(ft - c);
    for (int o = 32; o > 0; o >>= 1) v += __shfl_xor(v, o, 64);
    if ((t & 63) == 0) red[t >> 6] = v;
    __syncthreads();
    if (t == 0) { float s = 0; for (int i = 0; i < 16; ++i) s += red[i]; bc = s * (1.f / 1024.f); }
    __syncthreads();
    float sigma = bc;
    float w = __expf(-0.5f * (ft - c) * (ft - c) / (sigma * sigma));
    v = w;
    for (int o = 32; o > 0; o >>= 1) v += __shfl_xor(v, o, 64);
    if ((t & 63) == 0) red[t >> 6] = v;
    __syncthreads();
    if (t == 0) { float s = 0; for (int i = 0; i < 16; ++i) s += red[i]; bc = s; }
    __syncthreads();
    mask[t] = w / bc;
}

// ---------------------------------------------------------------------------
// LayerNorm + skip adapool. One block = 4 consecutive rows (one pool group).
// ---------------------------------------------------------------------------
__global__ __launch_bounds__(256) void ln_kernel(
    const float* __restrict__ x, const float* __restrict__ lng, const float* __restrict__ lnb,
    float* __restrict__ xn, float* __restrict__ skipo)
{
    __shared__ float red[8];
    __shared__ float mv[2];
    int t = threadIdx.x;
    int r0 = blockIdx.x * 4;
    float gg = lng[t], bbv = lnb[t];
    float acc = 0.f;
    for (int i = 0; i < 4; ++i) {
        size_t r = r0 + i;
        float v = x[r * 256 + t];
        float s = v, q = v * v;
        for (int o = 32; o > 0; o >>= 1) { s += __shfl_xor(s, o, 64); q += __shfl_xor(q, o, 64); }
        if ((t & 63) == 0) { red[t >> 6] = s; red[4 + (t >> 6)] = q; }
        __syncthreads();
        if (t == 0) {
            float S = red[0] + red[1] + red[2] + red[3];
            float Q = red[4] + red[5] + red[6] + red[7];
            float mu = S * (1.f / 256.f);
            mv[0] = mu;
            mv[1] = rsqrtf(Q * (1.f / 256.f) - mu * mu + 1e-5f);
        }
        __syncthreads();
        xn[r * 256 + t] = (v - mv[0]) * mv[1] * gg + bbv;
        acc += v;
        __syncthreads();
    }
    int b = r0 >> 12;
    int g = (r0 & 4095) >> 2;
    skipo[((size_t)b * TOK + g) * 256 + t] = acc * 0.25f;
}

// ---------------------------------------------------------------------------
// GEMM1: C[16384 x 768] = xn @ Wf1^T + bf1; route to z / softplus->h1 / ->g2.
// ---------------------------------------------------------------------------
__global__ __launch_bounds__(256) void gemm1_kernel(
    const float* __restrict__ A, const float* __restrict__ Bw, const float* __restrict__ bias,
    float* __restrict__ z, float* __restrict__ h1, float* __restrict__ g2)
{
    __shared__ __align__(16) float As[16][68];
    __shared__ __align__(16) float Bs[16][68];
    int tid = threadIdx.x;
    int m0 = blockIdx.x * 64;
    int j0 = blockIdx.y * 64;
    int lm = tid >> 2, kq = (tid & 3) * 4;
    int tx = tid & 15, ty = tid >> 4;
    float acc[4][4] = {};
    for (int k0 = 0; k0 < 256; k0 += 16) {
        float4 av = *(const float4*)&A[((size_t)(m0 + lm)) * 256 + k0 + kq];
        float4 bv = *(const float4*)&Bw[((size_t)(j0 + lm)) * 256 + k0 + kq];
        __syncthreads();
        As[kq + 0][lm] = av.x; As[kq + 1][lm] = av.y; As[kq + 2][lm] = av.z; As[kq + 3][lm] = av.w;
        Bs[kq + 0][lm] = bv.x; Bs[kq + 1][lm] = bv.y; Bs[kq + 2][lm] = bv.z; Bs[kq + 3][lm] = bv.w;
        __syncthreads();
#pragma unroll
        for (int kk = 0; kk < 16; ++kk) {
            float4 a4 = *(const float4*)&As[kk][ty * 4];
            float4 b4 = *(const float4*)&Bs[kk][tx * 4];
            float aa[4] = {a4.x, a4.y, a4.z, a4.w};
            float bb[4] = {b4.x, b4.y, b4.z, b4.w};
#pragma unroll
            for (int i = 0; i < 4; ++i)
#pragma unroll
                for (int jj = 0; jj < 4; ++jj)
                    acc[i][jj] = fmaf(aa[i], bb[jj], acc[i][jj]);
        }
    }
    int target = j0 >> 8;               // 0:z  1:h1  2:g2
    int jl = (j0 & 255) + tx * 4;
    float* outp = (target == 0) ? z : (target == 1 ? h1 : g2);
    bool actv = (target != 0);
    float bsv[4];
#pragma unroll
    for (int jj = 0; jj < 4; ++jj) bsv[jj] = bias[j0 + tx * 4 + jj];
#pragma unroll
    for (int i = 0; i < 4; ++i) {
        size_t r = m0 + ty * 4 + i;
        float vv[4];
#pragma unroll
        for (int jj = 0; jj < 4; ++jj) {
            float v = acc[i][jj] + bsv[jj];
            vv[jj] = actv ? softplusf(v) : v;
        }
        float4 o; o.x = vv[0]; o.y = vv[1]; o.z = vv[2]; o.w = vv[3];
        *(float4*)&outp[r * 256 + jl] = o;
    }
}

// ---------------------------------------------------------------------------
// GEMM2 (per dir): [delta_pre | Bm | Cm] = h @ Wf2^T + b2.  N=288 (5 tiles).
// ---------------------------------------------------------------------------
__global__ __launch_bounds__(256) void gemm2_kernel(
    const float* __restrict__ h1, const float* __restrict__ g2,
    const float* __restrict__ Wf, const float* __restrict__ bf2,
    const float* __restrict__ Wb, const float* __restrict__ bb2,
    float* __restrict__ dlf, float* __restrict__ dlb,
    float* __restrict__ BmF, float* __restrict__ CmF,
    float* __restrict__ BmB, float* __restrict__ CmB)
{
    __shared__ __align__(16) float As[16][68];
    __shared__ __align__(16) float Bs[16][68];
    int tid = threadIdx.x;
    int m0 = blockIdx.x * 64;
    int j0 = blockIdx.y * 64;
    int dir = blockIdx.z;
    const float* A    = dir ? g2 : h1;
    const float* Bw   = dir ? Wb : Wf;
    const float* bias = dir ? bb2 : bf2;
    float* dl = dir ? dlb : dlf;
    float* Bm = dir ? BmB : BmF;
    float* Cm = dir ? CmB : CmF;
    int lm = tid >> 2, kq = (tid & 3) * 4;
    int tx = tid & 15, ty = tid >> 4;
    int jr = j0 + lm;
    float acc[4][4] = {};
    for (int k0 = 0; k0 < 256; k0 += 16) {
        float4 av = *(const float4*)&A[((size_t)(m0 + lm)) * 256 + k0 + kq];
        float4 bv = make_float4(0.f, 0.f, 0.f, 0.f);
        if (jr < 288) bv = *(const float4*)&Bw[((size_t)jr) * 256 + k0 + kq];
        __syncthreads();
        As[kq + 0][lm] = av.x; As[kq + 1][lm] = av.y; As[kq + 2][lm] = av.z; As[kq + 3][lm] = av.w;
        Bs[kq + 0][lm] = bv.x; Bs[kq + 1][lm] = bv.y; Bs[kq + 2][lm] = bv.z; Bs[kq + 3][lm] = bv.w;
        __syncthreads();
#pragma unroll
        for (int kk = 0; kk < 16; ++kk) {
            float4 a4 = *(const float4*)&As[kk][ty * 4];
            float4 b4 = *(const float4*)&Bs[kk][tx * 4];
            float aa[4] = {a4.x, a4.y, a4.z, a4.w};
            float bb[4] = {b4.x, b4.y, b4.z, b4.w};
#pragma unroll
            for (int i = 0; i < 4; ++i)
#pragma unroll
                for (int jj = 0; jj < 4; ++jj)
                    acc[i][jj] = fmaf(aa[i], bb[jj], acc[i][jj]);
        }
    }
#pragma unroll
    for (int i = 0; i < 4; ++i) {
        size_t r = m0 + ty * 4 + i;
#pragma unroll
        for (int jj = 0; jj < 4; ++jj) {
            int jg = j0 + tx * 4 + jj;
            if (jg >= 288) continue;
            float v = acc[i][jj] + bias[jg];
            if (jg < 256)      dl[r * 256 + jg] = softplusf(v);
            else if (jg < 272) Bm[r * 16 + (jg - 256)] = v;
            else               Cm[r * 16 + (jg - 272)] = v;
        }
    }
}

// ---------------------------------------------------------------------------
// Scan pass 1: one thread per (dir,b,chunk,d); h[16] in registers.
// Coalesced delta/x loads (lane==d); B row is a wave-uniform 64B broadcast.
// Stores chunk aggregate (aprod, hend) as 4x float4 each.
// ---------------------------------------------------------------------------
__global__ __launch_bounds__(256) void scan1_kernel(
    const float* __restrict__ df, const float* __restrict__ db,
    const float* __restrict__ xf, const float* __restrict__ xb,
    const float* __restrict__ bmf, const float* __restrict__ bmb,
    const float* __restrict__ alogf, const float* __restrict__ alogb,
    float* __restrict__ aprod, float* __restrict__ hend)
{
    int d = threadIdx.x;
    int c = blockIdx.x, b = blockIdx.y, dir = blockIdx.z;
    const float* delta = dir ? db : df;
    const float* xin   = dir ? xb : xf;
    const float* Bm    = dir ? bmb : bmf;
    const float* Alog  = dir ? alogb : alogf;

    float A[16];
#pragma unroll
    for (int q = 0; q < 4; ++q) {
        float4 al = *(const float4*)&Alog[(size_t)d * 16 + q * 4];
        A[q * 4 + 0] = -__expf(al.x);
        A[q * 4 + 1] = -__expf(al.y);
        A[q * 4 + 2] = -__expf(al.z);
        A[q * 4 + 3] = -__expf(al.w);
    }
    float h[16];
#pragma unroll
    for (int n = 0; n < 16; ++n) h[n] = 0.f;
    float sd = 0.f;
    int base = c * CLEN;
#pragma unroll 2
    for (int it = 0; it < CLEN; ++it) {
        int t = dir ? (base + CLEN - 1 - it) : (base + it);
        size_t row = (size_t)b * LL + t;
        float dlt = delta[row * DD + d];
        float xv  = xin[row * DD + d];
        float common = dlt * xv;
        sd += dlt;
        const float4* Bp = (const float4*)&Bm[row * NS];
#pragma unroll
        for (int q = 0; q < 4; ++q) {
            float4 bq = Bp[q];
            float bb[4] = {bq.x, bq.y, bq.z, bq.w};
#pragma unroll
            for (int j = 0; j < 4; ++j) {
                int n = q * 4 + j;
                float a = __expf(dlt * A[n]);
                h[n] = fmaf(a, h[n], common * bb[j]);
            }
        }
    }
    size_t idx = ((((size_t)dir * BB + b) * DD + d) * NCH + c) * NS;
#pragma unroll
    for (int q = 0; q < 4; ++q) {
        float4 av, hv;
        av.x = __expf(sd * A[q * 4 + 0]);
        av.y = __expf(sd * A[q * 4 + 1]);
        av.z = __expf(sd * A[q * 4 + 2]);
        av.w = __expf(sd * A[q * 4 + 3]);
        hv.x = h[q * 4 + 0]; hv.y = h[q * 4 + 1]; hv.z = h[q * 4 + 2]; hv.w = h[q * 4 + 3];
        *(float4*)&aprod[idx + q * 4] = av;
        *(float4*)&hend[idx + q * 4] = hv;
    }
}

// ---------------------------------------------------------------------------
// Scan pass 2: chain the 64 chunk aggregates -> entering state per chunk.
// In place: hh holds hend on entry, hin on exit.
// ---------------------------------------------------------------------------
__global__ __launch_bounds__(256) void scan2_kernel(
    const float* __restrict__ aprod, float* __restrict__ hh)
{
    int g = blockIdx.x * 256 + threadIdx.x;
    int n = g & 15, d = (g >> 4) & 255, b = (g >> 12) & 3, dir = (g >> 14) & 1;
    size_t bidx = (((size_t)dir * BB + b) * DD + d) * NCH;
    float s = 0.f;
    if (!dir) {
        for (int c = 0; c < NCH; ++c) {
            size_t idx = (bidx + c) * NS + n;
            float a = aprod[idx], he = hh[idx];
            hh[idx] = s;
            s = fmaf(a, s, he);
        }
    } else {
        for (int c = NCH - 1; c >= 0; --c) {
            size_t idx = (bidx + c) * NS + n;
            float a = aprod[idx], he = hh[idx];
            hh[idx] = s;
            s = fmaf(a, s, he);
        }
    }
}

// ---------------------------------------------------------------------------
// Scan pass 3: replay chunk with true prefix; n-contraction in-register;
// accumulate adapool groups of 4 t; write pooled y only (b, g, d).
// ---------------------------------------------------------------------------
__global__ __launch_bounds__(256) void scan3_kernel(
    const float* __restrict__ df, const float* __restrict__ db,
    const float* __restrict__ xf, const float* __restrict__ xb,
    const float* __restrict__ bmf, const float* __restrict__ bmb,
    const float* __restrict__ cmf, const float* __restrict__ cmb,
    const float* __restrict__ alogf, const float* __restrict__ alogb,
    const float* __restrict__ Dfp, const float* __restrict__ Dbp,
    const float* __restrict__ hin,
    float* __restrict__ y1, float* __restrict__ y2)
{
    int d = threadIdx.x;
    int c = blockIdx.x, b = blockIdx.y, dir = blockIdx.z;
    const float* delta = dir ? db : df;
    const float* xin   = dir ? xb : xf;
    const float* Bm    = dir ? bmb : bmf;
    const float* Cm    = dir ? cmb : cmf;
    const float* Alog  = dir ? alogb : alogf;
    const float* Dv    = dir ? Dbp : Dfp;
    float* yout = dir ? y2 : y1;

    float A[16];
#pragma unroll
    for (int q = 0; q < 4; ++q) {
        float4 al = *(const float4*)&Alog[(size_t)d * 16 + q * 4];
        A[q * 4 + 0] = -__expf(al.x);
        A[q * 4 + 1] = -__expf(al.y);
        A[q * 4 + 2] = -__expf(al.z);
        A[q * 4 + 3] = -__expf(al.w);
    }
    float Dd = Dv[d];
    float h[16];
    size_t idx = ((((size_t)dir * BB + b) * DD + d) * NCH + c) * NS;
#pragma unroll
    for (int q = 0; q < 4; ++q) {
        float4 hv = *(const float4*)&hin[idx + q * 4];
        h[q * 4 + 0] = hv.x; h[q * 4 + 1] = hv.y; h[q * 4 + 2] = hv.z; h[q * 4 + 3] = hv.w;
    }
    int base = c * CLEN;
    float pool = 0.f;
#pragma unroll 2
    for (int it = 0; it < CLEN; ++it) {
        int t = dir ? (base + CLEN - 1 - it) : (base + it);
        size_t row = (size_t)b * LL + t;
        float dlt = delta[row * DD + d];
        float xv  = xin[row * DD + d];
        float common = dlt * xv;
        const float4* Bp = (const float4*)&Bm[row * NS];
        const float4* Cp = (const float4*)&Cm[row * NS];
        float yac = 0.f;
#pragma unroll
        for (int q = 0; q < 4; ++q) {
            float4 bq = Bp[q];
            float4 cq = Cp[q];
            float bb[4] = {bq.x, bq.y, bq.z, bq.w};
            float cc[4] = {cq.x, cq.y, cq.z, cq.w};
#pragma unroll
            for (int j = 0; j < 4; ++j) {
                int n = q * 4 + j;
                float a = __expf(dlt * A[n]);
                h[n] = fmaf(a, h[n], common * bb[j]);
                yac = fmaf(h[n], cc[j], yac);
            }
        }
        pool += yac + Dd * xv;
        bool gend = dir ? ((t & 3) == 0) : ((t & 3) == 3);
        if (gend) {
            yout[((size_t)b * TOK + (t >> 2)) * DD + d] = pool * 0.25f;
            pool = 0.f;
        }
    }
}

// ---------------------------------------------------------------------------
// Final: zp = silu(pool(z)); out = zp*(silu(y1*mask)+silu(y2*mask)) + skip
// ---------------------------------------------------------------------------
__global__ __launch_bounds__(256) void final_kernel(
    const float* __restrict__ z, const float* __restrict__ y1, const float* __restrict__ y2,
    const float* __restrict__ mask, const float* __restrict__ skipi, float* __restrict__ out)
{
    int p = blockIdx.x;
    int b = p >> 10, g = p & 1023;
    int d = threadIdx.x;
    size_t zr = ((size_t)b * LL + (size_t)g * 4) * DD + d;
    float zs = z[zr] + z[zr + 256] + z[zr + 512] + z[zr + 768];
    float zp = siluf(0.25f * zs);
    size_t ip = ((size_t)b * TOK + g) * DD + d;
    float mk = mask[g];
    float a1 = y1[ip] * mk, a2 = y2[ip] * mk;
    out[ip] = zp * (siluf(a1) + siluf(a2)) + skipi[ip];
}

// ---------------------------------------------------------------------------
extern "C" void kernel_launch(void* const* d_in, const int* in_sizes, int n_in,
                              void* d_out, int out_size, void* d_ws, size_t ws_size,
                              hipStream_t stream)
{
    const float* x      = (const float*)d_in[0];
    const float* ln_g   = (const float*)d_in[1];
    const float* ln_b   = (const float*)d_in[2];
    const float* W1     = (const float*)d_in[3];
    const float* b1     = (const float*)d_in[4];
    const float* W2     = (const float*)d_in[5];
    const float* b2     = (const float*)d_in[6];
    const float* Wcf    = (const float*)d_in[7];
    const float* bcf    = (const float*)d_in[8];
    const float* Wcb    = (const float*)d_in[9];
    const float* bcb    = (const float*)d_in[10];
    const float* Wdbc_f = (const float*)d_in[11];
    const float* Wdt_f  = (const float*)d_in[12];
    const float* bdt_f  = (const float*)d_in[13];
    const float* Alog_f = (const float*)d_in[14];
    const float* D_f    = (const float*)d_in[15];
    const float* Wdbc_b = (const float*)d_in[16];
    const float* Wdt_b  = (const float*)d_in[17];
    const float* bdt_b  = (const float*)d_in[18];
    const float* Alog_b = (const float*)d_in[19];
    const float* D_b    = (const float*)d_in[20];
    float* out = (float*)d_out;
    float* ws  = (float*)d_ws;

    float* xn   = ws + O_XN;
    float* zb   = ws + O_Z;
    float* h1b  = ws + O_H1;
    float* g2b  = ws + O_G2;
    float* dfb  = ws + O_DF;   // aliases xn (dead after gemm1)
    float* dbb  = ws + O_DB;
    float* bmf  = ws + O_BMF;
    float* cmf  = ws + O_CMF;
    float* bmb  = ws + O_BMB;
    float* cmb  = ws + O_CMB;
    float* skb  = ws + O_SKIP;
    float* y1b  = ws + O_Y1;
    float* y2b  = ws + O_Y2;
    float* wf1  = ws + O_WF1;
    float* bf1  = ws + O_BF1;
    float* wf2f = ws + O_WF2F;
    float* b2f  = ws + O_B2F;
    float* wf2b = ws + O_WF2B;
    float* b2b  = ws + O_B2B;
    float* apr  = ws + O_APROD;
    float* hnd  = ws + O_HEND;   // hend, then hin in place
    float* mkb  = ws + O_MASK;

    prep_wc_kernel<<<dim3(256, 2), 256, 0, stream>>>(W1, b1, W2, b2, Wcf, bcf, Wcb, bcb, wf1, bf1);
    prep_wdd_kernel<<<dim3(256, 2), 256, 0, stream>>>(Wdt_f, Wdbc_f, bdt_f, Wdt_b, Wdbc_b, bdt_b,
                                                      wf2f, b2f, wf2b, b2b);
    mask_kernel<<<1, 1024, 0, stream>>>(mkb);
    ln_kernel<<<4096, 256, 0, stream>>>(x, ln_g, ln_b, xn, skb);
    gemm1_kernel<<<dim3(256, 12), 256, 0, stream>>>(xn, wf1, bf1, zb, h1b, g2b);
    gemm2_kernel<<<dim3(256, 5, 2), 256, 0, stream>>>(h1b, g2b, wf2f, b2f, wf2b, b2b,
                                                      dfb, dbb, bmf, cmf, bmb, cmb);
    scan1_kernel<<<dim3(NCH, BB, 2), 256, 0, stream>>>(dfb, dbb, h1b, g2b, bmf, bmb,
                                                       Alog_f, Alog_b, apr, hnd);
    scan2_kernel<<<128, 256, 0, stream>>>(apr, hnd);
    scan3_kernel<<<dim3(NCH, BB, 2), 256, 0, stream>>>(dfb, dbb, h1b, g2b, bmf, bmb, cmf, cmb,
                                                       Alog_f, Alog_b, D_f, D_b, hnd, y1b, y2b);
    final_kernel<<<4096, 256, 0, stream>>>(zb, y1b, y2b, mkb, skb, out);
}

// Round 3
// 300.790 us; speedup vs baseline: 2.2073x; 1.4273x over previous
//
#include <hip/hip_runtime.h>
#include <math.h>

// ---------------------------------------------------------------------------
// VisionEncoderMambaBlock  (B=4, L=4096, D=256, d_state=16, T=1024)
// Round 2: both GEMMs moved to bf16 MFMA (16x16x32), m97-style 128x128 tile
// with global_load_lds width-16 staging in fragment-ordered LDS.
// Scan pipeline unchanged from round 1.
// ---------------------------------------------------------------------------

namespace {
constexpr int BB = 4;
constexpr int LL = 4096;
constexpr int DD = 256;
constexpr int NS = 16;       // d_state
constexpr int NCH = 64;
constexpr int CLEN = 64;     // LL / NCH
constexpr int TOK = 1024;

constexpr size_t NROW = (size_t)BB * LL;   // 16384
constexpr size_t NE   = NROW * DD;         // 4,194,304
constexpr size_t NP   = (size_t)BB * TOK * DD; // 1,048,576
constexpr size_t NBC  = NROW * NS;         // 262,144
constexpr size_t NAGG = 2ull * BB * DD * NCH * NS; // 4,194,304

// ws layout (float offsets).
// O_DF region: first NE/2 floats hold xn (bf16) for gemm1; gemm2 later
// overwrites the full NE floats with delta_f (xn dead by then).
constexpr size_t O_DF   = 0;
constexpr size_t O_Z    = NE;
constexpr size_t O_H1   = 2 * NE;
constexpr size_t O_G2   = 3 * NE;
constexpr size_t O_DB   = 4 * NE;
constexpr size_t O_H1X  = 5 * NE;            // bf16 h1 (NE elems = NE/2 floats)
constexpr size_t O_G2X  = 5 * NE + NE / 2;   // bf16 g2
constexpr size_t O_BMF  = 6 * NE;
constexpr size_t O_CMF  = O_BMF + NBC;
constexpr size_t O_BMB  = O_CMF + NBC;
constexpr size_t O_CMB  = O_BMB + NBC;
constexpr size_t O_SKIP = O_CMB + NBC;
constexpr size_t O_Y1   = O_SKIP + NP;
constexpr size_t O_Y2   = O_Y1 + NP;
constexpr size_t O_WF1  = O_Y2 + NP;             // 768x256 bf16 = 98304 floats
constexpr size_t O_BF1  = O_WF1 + 768 * 256 / 2; // 768 floats
constexpr size_t O_WF2F = O_BF1 + 768;           // 384x256 bf16 = 49152 floats
constexpr size_t O_B2F  = O_WF2F + 384 * 256 / 2;
constexpr size_t O_WF2B = O_B2F + 384;
constexpr size_t O_B2B  = O_WF2B + 384 * 256 / 2;
constexpr size_t O_APROD = O_B2B + 384;
constexpr size_t O_HEND = O_APROD + NAGG;        // hend, then hin in place
constexpr size_t O_MASK = O_HEND + NAGG;         // 1024
} // namespace

typedef __bf16 bf16x8 __attribute__((ext_vector_type(8)));
typedef float f32x4 __attribute__((ext_vector_type(4)));

__device__ __forceinline__ float softplusf(float x) {
    return fmaxf(x, 0.f) + log1pf(__expf(-fabsf(x)));
}
__device__ __forceinline__ float siluf(float x) {
    return x / (1.f + __expf(-x));
}
__device__ __forceinline__ void gl_lds16(const void* g, void* l) {
    __builtin_amdgcn_global_load_lds((const __attribute__((address_space(1))) unsigned int*)g,
                                     (__attribute__((address_space(3))) unsigned int*)l, 16, 0, 0);
}

// ---------------------------------------------------------------------------
// Weight prep: Wfused1 = [W1 ; Wcf@W2 ; Wcb@W2] (768x256) in bf16, biases f32.
// ---------------------------------------------------------------------------
__global__ __launch_bounds__(256) void prep_wc_kernel(
    const float* __restrict__ W1, const float* __restrict__ b1,
    const float* __restrict__ W2, const float* __restrict__ b2,
    const float* __restrict__ Wcf, const float* __restrict__ bcf,
    const float* __restrict__ Wcb, const float* __restrict__ bcb,
    __bf16* __restrict__ Wf1, float* __restrict__ bf1)
{
    int j = blockIdx.x, mat = blockIdx.y, k = threadIdx.x;
    const float* Wc = mat ? Wcb : Wcf;
    float acc = 0.f, accb = 0.f;
    for (int m = 0; m < 256; ++m) {
        float w = Wc[j * 256 + m];
        acc  = fmaf(w, W2[m * 256 + k], acc);
        accb = fmaf(w, b2[m], accb);
    }
    Wf1[(size_t)(256 + mat * 256 + j) * 256 + k] = (__bf16)acc;
    if (k == 0) bf1[256 + mat * 256 + j] = accb + (mat ? bcb[j] : bcf[j]);
    if (mat == 0) {
        Wf1[(size_t)j * 256 + k] = (__bf16)W1[j * 256 + k];
        if (k == 0) bf1[j] = b1[j];
    }
}

// ---------------------------------------------------------------------------
// Wf2 = [Wdt@Wdbc[:16] (256 rows) ; Wdbc[16:48] (32 rows) ; 0-pad to 384],
// bf16, per direction.  grid (384, 2) x 256.
// ---------------------------------------------------------------------------
__global__ __launch_bounds__(256) void prep_wdd_kernel(
    const float* __restrict__ Wdt_f, const float* __restrict__ Wdbc_f, const float* __restrict__ bdt_f,
    const float* __restrict__ Wdt_b, const float* __restrict__ Wdbc_b, const float* __restrict__ bdt_b,
    __bf16* __restrict__ Wf2f, float* __restrict__ b2f,
    __bf16* __restrict__ Wf2b, float* __restrict__ b2b)
{
    int j = blockIdx.x, mat = blockIdx.y, k = threadIdx.x;
    const float* Wdt  = mat ? Wdt_b : Wdt_f;
    const float* Wdbc = mat ? Wdbc_b : Wdbc_f;
    const float* bdt  = mat ? bdt_b : bdt_f;
    __bf16* Wf2 = mat ? Wf2b : Wf2f;
    float* b2x  = mat ? b2b : b2f;
    float val;
    if (j < 256) {
        float acc = 0.f;
#pragma unroll
        for (int m = 0; m < 16; ++m)
            acc = fmaf(Wdt[j * 16 + m], Wdbc[m * 256 + k], acc);
        val = acc;
    } else if (j < 288) {
        val = Wdbc[(16 + (j - 256)) * 256 + k];
    } else {
        val = 0.f;
    }
    Wf2[(size_t)j * 256 + k] = (__bf16)val;
    if (k == 0) b2x[j] = (j < 256) ? bdt[j] : 0.f;
}

// ---------------------------------------------------------------------------
// Gaussian mask (closed over T=1024); one block of 1024 threads.
// ---------------------------------------------------------------------------
__global__ __launch_bounds__(1024) void mask_kernel(float* __restrict__ mask)
{
    __shared__ float red[16];
    __shared__ float bc;
    int t = threadIdx.x;
    const float c = 512.f; // (T+1)//2
    float ft = (float)t;
    float v = fabsf(ft - c);
    for (int o = 32; o > 0; o >>= 1) v += __shfl_xor(v, o, 64);
    if ((t & 63) == 0) red[t >> 6] = v;
    __syncthreads();
    if (t == 0) { float s = 0; for (int i = 0; i < 16; ++i) s += red[i]; bc = s * (1.f / 1024.f); }
    __syncthreads();
    float sigma = bc;
    float w = __expf(-0.5f * (ft - c) * (ft - c) / (sigma * sigma));
    v = w;
    for (int o = 32; o > 0; o >>= 1) v += __shfl_xor(v, o, 64);
    if ((t & 63) == 0) red[t >> 6] = v;
    __syncthreads();
    if (t == 0) { float s = 0; for (int i = 0; i < 16; ++i) s += red[i]; bc = s; }
    __syncthreads();
    mask[t] = w / bc;
}

// ---------------------------------------------------------------------------
// LayerNorm (bf16 out for MFMA gemm1) + skip adapool.
// ---------------------------------------------------------------------------
__global__ __launch_bounds__(256) void ln_kernel(
    const float* __restrict__ x, const float* __restrict__ lng, const float* __restrict__ lnb,
    __bf16* __restrict__ xn, float* __restrict__ skipo)
{
    __shared__ float red[8];
    __shared__ float mv[2];
    int t = threadIdx.x;
    int r0 = blockIdx.x * 4;
    float gg = lng[t], bbv = lnb[t];
    float acc = 0.f;
    for (int i = 0; i < 4; ++i) {
        size_t r = r0 + i;
        float v = x[r * 256 + t];
        float s = v, q = v * v;
        for (int o = 32; o > 0; o >>= 1) { s += __shfl_xor(s, o, 64); q += __shfl_xor(q, o, 64); }
        if ((t & 63) == 0) { red[t >> 6] = s; red[4 + (t >> 6)] = q; }
        __syncthreads();
        if (t == 0) {
            float S = red[0] + red[1] + red[2] + red[3];
            float Q = red[4] + red[5] + red[6] + red[7];
            float mu = S * (1.f / 256.f);
            mv[0] = mu;
            mv[1] = rsqrtf(Q * (1.f / 256.f) - mu * mu + 1e-5f);
        }
        __syncthreads();
        xn[r * 256 + t] = (__bf16)((v - mv[0]) * mv[1] * gg + bbv);
        acc += v;
        __syncthreads();
    }
    int b = r0 >> 12;
    int g = (r0 & 4095) >> 2;
    skipo[((size_t)b * TOK + g) * 256 + t] = acc * 0.25f;
}

// ---------------------------------------------------------------------------
// MFMA GEMM1: C[16384 x 768] = xn(bf16) @ Wf1^T(bf16) + bf1.
// 128x128 tile, BK=32, 4 waves x (4x4 MFMAs of 16x16x32).
// LDS is fragment-ordered: subblock s (16 rows x 32 k) = 64 lanes x 16B,
// staged via global_load_lds (wave-uniform base + lane*16).
// Epilogue routes: j<256 -> z (f32); 256..511 -> softplus -> h1 (f32+bf16);
// 512..767 -> softplus -> g2 (f32+bf16).
// ---------------------------------------------------------------------------
__global__ __launch_bounds__(256) void gemm1_mfma(
    const __bf16* __restrict__ A, const __bf16* __restrict__ Bw, const float* __restrict__ bias,
    float* __restrict__ z, float* __restrict__ h1, float* __restrict__ g2,
    __bf16* __restrict__ h1x, __bf16* __restrict__ g2x)
{
    __shared__ __align__(16) __bf16 As[4096];
    __shared__ __align__(16) __bf16 Bs[4096];
    int tid = threadIdx.x;
    int lane = tid & 63, wv = tid >> 6;
    int wr = wv >> 1, wc = wv & 1;
    int lm = lane & 15, lq = lane >> 4;
    int m0 = blockIdx.x << 7, n0 = blockIdx.y << 7;

    const __bf16* ga0 = A  + (size_t)(m0 + wv * 32 + lm) * 256 + lq * 8;
    const __bf16* ga1 = ga0 + 16 * 256;
    const __bf16* gb0 = Bw + (size_t)(n0 + wv * 32 + lm) * 256 + lq * 8;
    const __bf16* gb1 = gb0 + 16 * 256;
    __bf16* la0 = &As[(wv * 2    ) * 512];
    __bf16* la1 = &As[(wv * 2 + 1) * 512];
    __bf16* lb0 = &Bs[(wv * 2    ) * 512];
    __bf16* lb1 = &Bs[(wv * 2 + 1) * 512];

    f32x4 acc[4][4];
#pragma unroll
    for (int i = 0; i < 4; ++i)
#pragma unroll
        for (int j = 0; j < 4; ++j) acc[i][j] = 0;

    for (int k0 = 0; k0 < 256; k0 += 32) {
        __syncthreads();
        gl_lds16(ga0 + k0, la0);
        gl_lds16(ga1 + k0, la1);
        gl_lds16(gb0 + k0, lb0);
        gl_lds16(gb1 + k0, lb1);
        __syncthreads();
        bf16x8 af[4], bfr[4];
#pragma unroll
        for (int i = 0; i < 4; ++i)
            af[i] = *(const bf16x8*)&As[(wr * 4 + i) * 512 + lane * 8];
#pragma unroll
        for (int j = 0; j < 4; ++j)
            bfr[j] = *(const bf16x8*)&Bs[(wc * 4 + j) * 512 + lane * 8];
#pragma unroll
        for (int i = 0; i < 4; ++i)
#pragma unroll
            for (int j = 0; j < 4; ++j)
                acc[i][j] = __builtin_amdgcn_mfma_f32_16x16x32_bf16(af[i], bfr[j], acc[i][j], 0, 0, 0);
    }

    int target = blockIdx.y >> 1;  // 0:z 1:h1 2:g2 (BN=128, 256-aligned groups)
#pragma unroll
    for (int j = 0; j < 4; ++j) {
        int col = n0 + wc * 64 + j * 16 + lm;
        float bv = bias[col];
        int cl = col & 255;
#pragma unroll
        for (int i = 0; i < 4; ++i) {
            int row = m0 + wr * 64 + i * 16 + lq * 4;
#pragma unroll
            for (int r = 0; r < 4; ++r) {
                float v = acc[i][j][r] + bv;
                size_t off = (size_t)(row + r) * 256 + cl;
                if (target == 0) {
                    z[off] = v;
                } else {
                    float sp = softplusf(v);
                    if (target == 1) { h1[off] = sp; h1x[off] = (__bf16)sp; }
                    else             { g2[off] = sp; g2x[off] = (__bf16)sp; }
                }
            }
        }
    }
}

// ---------------------------------------------------------------------------
// MFMA GEMM2 (per dir): [delta|Bm|Cm|pad] = h(bf16) @ Wf2^T(bf16) + b2.
// N padded to 384 (3 tiles of 128). grid (128, 3, 2).
// ---------------------------------------------------------------------------
__global__ __launch_bounds__(256) void gemm2_mfma(
    const __bf16* __restrict__ h1x, const __bf16* __restrict__ g2x,
    const __bf16* __restrict__ Wf, const float* __restrict__ bf2,
    const __bf16* __restrict__ Wb, const float* __restrict__ bb2,
    float* __restrict__ dlf, float* __restrict__ dlb,
    float* __restrict__ BmF, float* __restrict__ CmF,
    float* __restrict__ BmB, float* __restrict__ CmB)
{
    __shared__ __align__(16) __bf16 As[4096];
    __shared__ __align__(16) __bf16 Bs[4096];
    int tid = threadIdx.x;
    int lane = tid & 63, wv = tid >> 6;
    int wr = wv >> 1, wc = wv & 1;
    int lm = lane & 15, lq = lane >> 4;
    int m0 = blockIdx.x << 7, n0 = blockIdx.y << 7;
    int dir = blockIdx.z;
    const __bf16* A    = dir ? g2x : h1x;
    const __bf16* Bw   = dir ? Wb : Wf;
    const float* bias  = dir ? bb2 : bf2;
    float* dl = dir ? dlb : dlf;
    float* Bm = dir ? BmB : BmF;
    float* Cm = dir ? CmB : CmF;

    const __bf16* ga0 = A  + (size_t)(m0 + wv * 32 + lm) * 256 + lq * 8;
    const __bf16* ga1 = ga0 + 16 * 256;
    const __bf16* gb0 = Bw + (size_t)(n0 + wv * 32 + lm) * 256 + lq * 8;
    const __bf16* gb1 = gb0 + 16 * 256;
    __bf16* la0 = &As[(wv * 2    ) * 512];
    __bf16* la1 = &As[(wv * 2 + 1) * 512];
    __bf16* lb0 = &Bs[(wv * 2    ) * 512];
    __bf16* lb1 = &Bs[(wv * 2 + 1) * 512];

    f32x4 acc[4][4];
#pragma unroll
    for (int i = 0; i < 4; ++i)
#pragma unroll
        for (int j = 0; j < 4; ++j) acc[i][j] = 0;

    for (int k0 = 0; k0 < 256; k0 += 32) {
        __syncthreads();
        gl_lds16(ga0 + k0, la0);
        gl_lds16(ga1 + k0, la1);
        gl_lds16(gb0 + k0, lb0);
        gl_lds16(gb1 + k0, lb1);
        __syncthreads();
        bf16x8 af[4], bfr[4];
#pragma unroll
        for (int i = 0; i < 4; ++i)
            af[i] = *(const bf16x8*)&As[(wr * 4 + i) * 512 + lane * 8];
#pragma unroll
        for (int j = 0; j < 4; ++j)
            bfr[j] = *(const bf16x8*)&Bs[(wc * 4 + j) * 512 + lane * 8];
#pragma unroll
        for (int i = 0; i < 4; ++i)
#pragma unroll
            for (int j = 0; j < 4; ++j)
                acc[i][j] = __builtin_amdgcn_mfma_f32_16x16x32_bf16(af[i], bfr[j], acc[i][j], 0, 0, 0);
    }

#pragma unroll
    for (int j = 0; j < 4; ++j) {
        int col = n0 + wc * 64 + j * 16 + lm;
        if (col >= 288) continue;
        float bv = bias[col];
#pragma unroll
        for (int i = 0; i < 4; ++i) {
            int row = m0 + wr * 64 + i * 16 + lq * 4;
#pragma unroll
            for (int r = 0; r < 4; ++r) {
                float v = acc[i][j][r] + bv;
                size_t rr = (size_t)(row + r);
                if (col < 256)       dl[rr * 256 + col] = softplusf(v);
                else if (col < 272)  Bm[rr * 16 + (col - 256)] = v;
                else                 Cm[rr * 16 + (col - 272)] = v;
            }
        }
    }
}

// ---------------------------------------------------------------------------
// Scan pass 1: one thread per (dir,b,chunk,d); h[16] in registers.
// ---------------------------------------------------------------------------
__global__ __launch_bounds__(256) void scan1_kernel(
    const float* __restrict__ df, const float* __restrict__ db,
    const float* __restrict__ xf, const float* __restrict__ xb,
    const float* __restrict__ bmf, const float* __restrict__ bmb,
    const float* __restrict__ alogf, const float* __restrict__ alogb,
    float* __restrict__ aprod, float* __restrict__ hend)
{
    int d = threadIdx.x;
    int c = blockIdx.x, b = blockIdx.y, dir = blockIdx.z;
    const float* delta = dir ? db : df;
    const float* xin   = dir ? xb : xf;
    const float* Bm    = dir ? bmb : bmf;
    const float* Alog  = dir ? alogb : alogf;

    float A[16];
#pragma unroll
    for (int q = 0; q < 4; ++q) {
        float4 al = *(const float4*)&Alog[(size_t)d * 16 + q * 4];
        A[q * 4 + 0] = -__expf(al.x);
        A[q * 4 + 1] = -__expf(al.y);
        A[q * 4 + 2] = -__expf(al.z);
        A[q * 4 + 3] = -__expf(al.w);
    }
    float h[16];
#pragma unroll
    for (int n = 0; n < 16; ++n) h[n] = 0.f;
    float sd = 0.f;
    int base = c * CLEN;
#pragma unroll 2
    for (int it = 0; it < CLEN; ++it) {
        int t = dir ? (base + CLEN - 1 - it) : (base + it);
        size_t row = (size_t)b * LL + t;
        float dlt = delta[row * DD + d];
        float xv  = xin[row * DD + d];
        float common = dlt * xv;
        sd += dlt;
        const float4* Bp = (const float4*)&Bm[row * NS];
#pragma unroll
        for (int q = 0; q < 4; ++q) {
            float4 bq = Bp[q];
            float bb[4] = {bq.x, bq.y, bq.z, bq.w};
#pragma unroll
            for (int j = 0; j < 4; ++j) {
                int n = q * 4 + j;
                float a = __expf(dlt * A[n]);
                h[n] = fmaf(a, h[n], common * bb[j]);
            }
        }
    }
    size_t idx = ((((size_t)dir * BB + b) * DD + d) * NCH + c) * NS;
#pragma unroll
    for (int q = 0; q < 4; ++q) {
        float4 av, hv;
        av.x = __expf(sd * A[q * 4 + 0]);
        av.y = __expf(sd * A[q * 4 + 1]);
        av.z = __expf(sd * A[q * 4 + 2]);
        av.w = __expf(sd * A[q * 4 + 3]);
        hv.x = h[q * 4 + 0]; hv.y = h[q * 4 + 1]; hv.z = h[q * 4 + 2]; hv.w = h[q * 4 + 3];
        *(float4*)&aprod[idx + q * 4] = av;
        *(float4*)&hend[idx + q * 4] = hv;
    }
}

// ---------------------------------------------------------------------------
// Scan pass 2: chain the 64 chunk aggregates; in place hend -> hin.
// ---------------------------------------------------------------------------
__global__ __launch_bounds__(256) void scan2_kernel(
    const float* __restrict__ aprod, float* __restrict__ hh)
{
    int g = blockIdx.x * 256 + threadIdx.x;
    int n = g & 15, d = (g >> 4) & 255, b = (g >> 12) & 3, dir = (g >> 14) & 1;
    size_t bidx = (((size_t)dir * BB + b) * DD + d) * NCH;
    float s = 0.f;
    if (!dir) {
        for (int c = 0; c < NCH; ++c) {
            size_t idx = (bidx + c) * NS + n;
            float a = aprod[idx], he = hh[idx];
            hh[idx] = s;
            s = fmaf(a, s, he);
        }
    } else {
        for (int c = NCH - 1; c >= 0; --c) {
            size_t idx = (bidx + c) * NS + n;
            float a = aprod[idx], he = hh[idx];
            hh[idx] = s;
            s = fmaf(a, s, he);
        }
    }
}

// ---------------------------------------------------------------------------
// Scan pass 3: replay with true prefix; in-register n-contraction; pooled y.
// ---------------------------------------------------------------------------
__global__ __launch_bounds__(256) void scan3_kernel(
    const float* __restrict__ df, const float* __restrict__ db,
    const float* __restrict__ xf, const float* __restrict__ xb,
    const float* __restrict__ bmf, const float* __restrict__ bmb,
    const float* __restrict__ cmf, const float* __restrict__ cmb,
    const float* __restrict__ alogf, const float* __restrict__ alogb,
    const float* __restrict__ Dfp, const float* __restrict__ Dbp,
    const float* __restrict__ hin,
    float* __restrict__ y1, float* __restrict__ y2)
{
    int d = threadIdx.x;
    int c = blockIdx.x, b = blockIdx.y, dir = blockIdx.z;
    const float* delta = dir ? db : df;
    const float* xin   = dir ? xb : xf;
    const float* Bm    = dir ? bmb : bmf;
    const float* Cm    = dir ? cmb : cmf;
    const float* Alog  = dir ? alogb : alogf;
    const float* Dv    = dir ? Dbp : Dfp;
    float* yout = dir ? y2 : y1;

    float A[16];
#pragma unroll
    for (int q = 0; q < 4; ++q) {
        float4 al = *(const float4*)&Alog[(size_t)d * 16 + q * 4];
        A[q * 4 + 0] = -__expf(al.x);
        A[q * 4 + 1] = -__expf(al.y);
        A[q * 4 + 2] = -__expf(al.z);
        A[q * 4 + 3] = -__expf(al.w);
    }
    float Dd = Dv[d];
    float h[16];
    size_t idx = ((((size_t)dir * BB + b) * DD + d) * NCH + c) * NS;
#pragma unroll
    for (int q = 0; q < 4; ++q) {
        float4 hv = *(const float4*)&hin[idx + q * 4];
        h[q * 4 + 0] = hv.x; h[q * 4 + 1] = hv.y; h[q * 4 + 2] = hv.z; h[q * 4 + 3] = hv.w;
    }
    int base = c * CLEN;
    float pool = 0.f;
#pragma unroll 2
    for (int it = 0; it < CLEN; ++it) {
        int t = dir ? (base + CLEN - 1 - it) : (base + it);
        size_t row = (size_t)b * LL + t;
        float dlt = delta[row * DD + d];
        float xv  = xin[row * DD + d];
        float common = dlt * xv;
        const float4* Bp = (const float4*)&Bm[row * NS];
        const float4* Cp = (const float4*)&Cm[row * NS];
        float yac = 0.f;
#pragma unroll
        for (int q = 0; q < 4; ++q) {
            float4 bq = Bp[q];
            float4 cq = Cp[q];
            float bb[4] = {bq.x, bq.y, bq.z, bq.w};
            float cc[4] = {cq.x, cq.y, cq.z, cq.w};
#pragma unroll
            for (int j = 0; j < 4; ++j) {
                int n = q * 4 + j;
                float a = __expf(dlt * A[n]);
                h[n] = fmaf(a, h[n], common * bb[j]);
                yac = fmaf(h[n], cc[j], yac);
            }
        }
        pool += yac + Dd * xv;
        bool gend = dir ? ((t & 3) == 0) : ((t & 3) == 3);
        if (gend) {
            yout[((size_t)b * TOK + (t >> 2)) * DD + d] = pool * 0.25f;
            pool = 0.f;
        }
    }
}

// ---------------------------------------------------------------------------
// Final: zp = silu(pool(z)); out = zp*(silu(y1*mask)+silu(y2*mask)) + skip
// ---------------------------------------------------------------------------
__global__ __launch_bounds__(256) void final_kernel(
    const float* __restrict__ z, const float* __restrict__ y1, const float* __restrict__ y2,
    const float* __restrict__ mask, const float* __restrict__ skipi, float* __restrict__ out)
{
    int p = blockIdx.x;
    int b = p >> 10, g = p & 1023;
    int d = threadIdx.x;
    size_t zr = ((size_t)b * LL + (size_t)g * 4) * DD + d;
    float zs = z[zr] + z[zr + 256] + z[zr + 512] + z[zr + 768];
    float zp = siluf(0.25f * zs);
    size_t ip = ((size_t)b * TOK + g) * DD + d;
    float mk = mask[g];
    float a1 = y1[ip] * mk, a2 = y2[ip] * mk;
    out[ip] = zp * (siluf(a1) + siluf(a2)) + skipi[ip];
}

// ---------------------------------------------------------------------------
extern "C" void kernel_launch(void* const* d_in, const int* in_sizes, int n_in,
                              void* d_out, int out_size, void* d_ws, size_t ws_size,
                              hipStream_t stream)
{
    const float* x      = (const float*)d_in[0];
    const float* ln_g   = (const float*)d_in[1];
    const float* ln_b   = (const float*)d_in[2];
    const float* W1     = (const float*)d_in[3];
    const float* b1     = (const float*)d_in[4];
    const float* W2     = (const float*)d_in[5];
    const float* b2     = (const float*)d_in[6];
    const float* Wcf    = (const float*)d_in[7];
    const float* bcf    = (const float*)d_in[8];
    const float* Wcb    = (const float*)d_in[9];
    const float* bcb    = (const float*)d_in[10];
    const float* Wdbc_f = (const float*)d_in[11];
    const float* Wdt_f  = (const float*)d_in[12];
    const float* bdt_f  = (const float*)d_in[13];
    const float* Alog_f = (const float*)d_in[14];
    const float* D_f    = (const float*)d_in[15];
    const float* Wdbc_b = (const float*)d_in[16];
    const float* Wdt_b  = (const float*)d_in[17];
    const float* bdt_b  = (const float*)d_in[18];
    const float* Alog_b = (const float*)d_in[19];
    const float* D_b    = (const float*)d_in[20];
    float* out = (float*)d_out;
    float* ws  = (float*)d_ws;

    __bf16* xnb = (__bf16*)(ws + O_DF);   // xn bf16; region later reused as df
    float* zb   = ws + O_Z;
    float* h1b  = ws + O_H1;
    float* g2b  = ws + O_G2;
    float* dfb  = ws + O_DF;
    float* dbb  = ws + O_DB;
    __bf16* h1x = (__bf16*)(ws + O_H1X);
    __bf16* g2x = (__bf16*)(ws + O_G2X);
    float* bmf  = ws + O_BMF;
    float* cmf  = ws + O_CMF;
    float* bmb  = ws + O_BMB;
    float* cmb  = ws + O_CMB;
    float* skb  = ws + O_SKIP;
    float* y1b  = ws + O_Y1;
    float* y2b  = ws + O_Y2;
    __bf16* wf1 = (__bf16*)(ws + O_WF1);
    float* bf1  = ws + O_BF1;
    __bf16* wf2f = (__bf16*)(ws + O_WF2F);
    float* b2f  = ws + O_B2F;
    __bf16* wf2b = (__bf16*)(ws + O_WF2B);
    float* b2b  = ws + O_B2B;
    float* apr  = ws + O_APROD;
    float* hnd  = ws + O_HEND;   // hend, then hin in place
    float* mkb  = ws + O_MASK;

    prep_wc_kernel<<<dim3(256, 2), 256, 0, stream>>>(W1, b1, W2, b2, Wcf, bcf, Wcb, bcb, wf1, bf1);
    prep_wdd_kernel<<<dim3(384, 2), 256, 0, stream>>>(Wdt_f, Wdbc_f, bdt_f, Wdt_b, Wdbc_b, bdt_b,
                                                      wf2f, b2f, wf2b, b2b);
    mask_kernel<<<1, 1024, 0, stream>>>(mkb);
    ln_kernel<<<4096, 256, 0, stream>>>(x, ln_g, ln_b, xnb, skb);
    gemm1_mfma<<<dim3(128, 6), 256, 0, stream>>>(xnb, wf1, bf1, zb, h1b, g2b, h1x, g2x);
    gemm2_mfma<<<dim3(128, 3, 2), 256, 0, stream>>>(h1x, g2x, wf2f, b2f, wf2b, b2b,
                                                    dfb, dbb, bmf, cmf, bmb, cmb);
    scan1_kernel<<<dim3(NCH, BB, 2), 256, 0, stream>>>(dfb, dbb, h1b, g2b, bmf, bmb,
                                                       Alog_f, Alog_b, apr, hnd);
    scan2_kernel<<<128, 256, 0, stream>>>(apr, hnd);
    scan3_kernel<<<dim3(NCH, BB, 2), 256, 0, stream>>>(dfb, dbb, h1b, g2b, bmf, bmb, cmf, cmb,
                                                       Alog_f, Alog_b, D_f, D_b, hnd, y1b, y2b);
    final_kernel<<<4096, 256, 0, stream>>>(zb, y1b, y2b, mkb, skb, out);
}

// Round 4
// 252.178 us; speedup vs baseline: 2.6328x; 1.1928x over previous
//
#include <hip/hip_runtime.h>
#include <math.h>

// ---------------------------------------------------------------------------
// VisionEncoderMambaBlock  (B=4, L=4096, D=256, d_state=16, T=1024)
// Round 3:
//  - all SSM intermediates bf16 (delta/B/C/h1/g2); z adapool+silu fused into
//    gemm1 epilogue (zp f32, 4 MB instead of z 16.8 MB)
//  - scan exp(delta*A_n) via power chain: A_n == -(n+1) (runtime-verified,
//    generic-exp fallback) -> 1 exp + 15 muls instead of 16 exps per (t,d)
//  - softplus via fast __logf
// ---------------------------------------------------------------------------

namespace {
constexpr int BB = 4;
constexpr int LL = 4096;
constexpr int DD = 256;
constexpr int NS = 16;       // d_state
constexpr int NCH = 64;
constexpr int CLEN = 64;     // LL / NCH
constexpr int TOK = 1024;

constexpr size_t NROW = (size_t)BB * LL;   // 16384
constexpr size_t NE   = NROW * DD;         // 4,194,304
constexpr size_t NP   = (size_t)BB * TOK * DD; // 1,048,576
constexpr size_t NBC  = NROW * NS;         // 262,144
constexpr size_t NAGG = 2ull * BB * DD * NCH * NS; // 4,194,304

// ws layout (float offsets). bf16 buffers use half their element count.
constexpr size_t O_XN   = 0;                    // xn bf16; later dlf bf16
constexpr size_t O_DLF  = O_XN;                 // alias (xn dead after gemm1)
constexpr size_t O_DLB  = NE / 2;               // delta_b bf16
constexpr size_t O_H1X  = NE;                   // h1 bf16
constexpr size_t O_G2X  = NE + NE / 2;          // g2 bf16
constexpr size_t O_BMF  = 2 * NE;               // bf16 NBC
constexpr size_t O_CMF  = O_BMF + NBC / 2;
constexpr size_t O_BMB  = O_CMF + NBC / 2;
constexpr size_t O_CMB  = O_BMB + NBC / 2;
constexpr size_t O_ZP   = O_CMB + NBC / 2;      // zp f32 (B,TOK,D)
constexpr size_t O_SKIP = O_ZP + NP;
constexpr size_t O_Y1   = O_SKIP + NP;
constexpr size_t O_Y2   = O_Y1 + NP;
constexpr size_t O_WF1  = O_Y2 + NP;            // 768x256 bf16
constexpr size_t O_BF1  = O_WF1 + 768 * 256 / 2;
constexpr size_t O_WF2F = O_BF1 + 768;          // 384x256 bf16
constexpr size_t O_B2F  = O_WF2F + 384 * 256 / 2;
constexpr size_t O_WF2B = O_B2F + 384;
constexpr size_t O_B2B  = O_WF2B + 384 * 256 / 2;
constexpr size_t O_APROD = O_B2B + 384;         // f32 NAGG
constexpr size_t O_HEND = O_APROD + NAGG;       // f32 NAGG; hin in place
constexpr size_t O_MASK = O_HEND + NAGG;        // 1024
} // namespace

typedef __bf16 bf16x8 __attribute__((ext_vector_type(8)));
typedef float f32x4 __attribute__((ext_vector_type(4)));

__device__ __forceinline__ float softplusf(float x) {
    return fmaxf(x, 0.f) + __logf(1.f + __expf(-fabsf(x)));
}
__device__ __forceinline__ float siluf(float x) {
    return x / (1.f + __expf(-x));
}
__device__ __forceinline__ void gl_lds16(const void* g, void* l) {
    __builtin_amdgcn_global_load_lds((const __attribute__((address_space(1))) unsigned int*)g,
                                     (__attribute__((address_space(3))) unsigned int*)l, 16, 0, 0);
}
// p[n] = e1^(n+1), log-depth-4 chain (15 muls)
__device__ __forceinline__ void pow_chain(float e1, float* p) {
    p[0] = e1;
    p[1] = e1 * e1;
    p[2] = p[1] * e1;
    p[3] = p[1] * p[1];
    p[4] = p[3] * p[0];
    p[5] = p[3] * p[1];
    p[6] = p[3] * p[2];
    p[7] = p[3] * p[3];
    p[8]  = p[7] * p[0];
    p[9]  = p[7] * p[1];
    p[10] = p[7] * p[2];
    p[11] = p[7] * p[3];
    p[12] = p[7] * p[4];
    p[13] = p[7] * p[5];
    p[14] = p[7] * p[6];
    p[15] = p[7] * p[7];
}

// ---------------------------------------------------------------------------
// Weight prep: Wfused1 = [W1 ; Wcf@W2 ; Wcb@W2] (768x256) in bf16, biases f32.
// ---------------------------------------------------------------------------
__global__ __launch_bounds__(256) void prep_wc_kernel(
    const float* __restrict__ W1, const float* __restrict__ b1,
    const float* __restrict__ W2, const float* __restrict__ b2,
    const float* __restrict__ Wcf, const float* __restrict__ bcf,
    const float* __restrict__ Wcb, const float* __restrict__ bcb,
    __bf16* __restrict__ Wf1, float* __restrict__ bf1)
{
    int j = blockIdx.x, mat = blockIdx.y, k = threadIdx.x;
    const float* Wc = mat ? Wcb : Wcf;
    float acc = 0.f, accb = 0.f;
    for (int m = 0; m < 256; ++m) {
        float w = Wc[j * 256 + m];
        acc  = fmaf(w, W2[m * 256 + k], acc);
        accb = fmaf(w, b2[m], accb);
    }
    Wf1[(size_t)(256 + mat * 256 + j) * 256 + k] = (__bf16)acc;
    if (k == 0) bf1[256 + mat * 256 + j] = accb + (mat ? bcb[j] : bcf[j]);
    if (mat == 0) {
        Wf1[(size_t)j * 256 + k] = (__bf16)W1[j * 256 + k];
        if (k == 0) bf1[j] = b1[j];
    }
}

// ---------------------------------------------------------------------------
// Wf2 = [Wdt@Wdbc[:16] (256) ; Wdbc[16:48] (32) ; 0-pad to 384], bf16.
// ---------------------------------------------------------------------------
__global__ __launch_bounds__(256) void prep_wdd_kernel(
    const float* __restrict__ Wdt_f, const float* __restrict__ Wdbc_f, const float* __restrict__ bdt_f,
    const float* __restrict__ Wdt_b, const float* __restrict__ Wdbc_b, const float* __restrict__ bdt_b,
    __bf16* __restrict__ Wf2f, float* __restrict__ b2f,
    __bf16* __restrict__ Wf2b, float* __restrict__ b2b)
{
    int j = blockIdx.x, mat = blockIdx.y, k = threadIdx.x;
    const float* Wdt  = mat ? Wdt_b : Wdt_f;
    const float* Wdbc = mat ? Wdbc_b : Wdbc_f;
    const float* bdt  = mat ? bdt_b : bdt_f;
    __bf16* Wf2 = mat ? Wf2b : Wf2f;
    float* b2x  = mat ? b2b : b2f;
    float val;
    if (j < 256) {
        float acc = 0.f;
#pragma unroll
        for (int m = 0; m < 16; ++m)
            acc = fmaf(Wdt[j * 16 + m], Wdbc[m * 256 + k], acc);
        val = acc;
    } else if (j < 288) {
        val = Wdbc[(16 + (j - 256)) * 256 + k];
    } else {
        val = 0.f;
    }
    Wf2[(size_t)j * 256 + k] = (__bf16)val;
    if (k == 0) b2x[j] = (j < 256) ? bdt[j] : 0.f;
}

// ---------------------------------------------------------------------------
// Gaussian mask (T=1024); one block of 1024 threads.
// ---------------------------------------------------------------------------
__global__ __launch_bounds__(1024) void mask_kernel(float* __restrict__ mask)
{
    __shared__ float red[16];
    __shared__ float bc;
    int t = threadIdx.x;
    const float c = 512.f;
    float ft = (float)t;
    float v = fabsf(ft - c);
    for (int o = 32; o > 0; o >>= 1) v += __shfl_xor(v, o, 64);
    if ((t & 63) == 0) red[t >> 6] = v;
    __syncthreads();
    if (t == 0) { float s = 0; for (int i = 0; i < 16; ++i) s += red[i]; bc = s * (1.f / 1024.f); }
    __syncthreads();
    float sigma = bc;
    float w = __expf(-0.5f * (ft - c) * (ft - c) / (sigma * sigma));
    v = w;
    for (int o = 32; o > 0; o >>= 1) v += __shfl_xor(v, o, 64);
    if ((t & 63) == 0) red[t >> 6] = v;
    __syncthreads();
    if (t == 0) { float s = 0; for (int i = 0; i < 16; ++i) s += red[i]; bc = s; }
    __syncthreads();
    mask[t] = w / bc;
}

// ---------------------------------------------------------------------------
// LayerNorm (bf16 out) + skip adapool.
// ---------------------------------------------------------------------------
__global__ __launch_bounds__(256) void ln_kernel(
    const float* __restrict__ x, const float* __restrict__ lng, const float* __restrict__ lnb,
    __bf16* __restrict__ xn, float* __restrict__ skipo)
{
    __shared__ float red[8];
    __shared__ float mv[2];
    int t = threadIdx.x;
    int r0 = blockIdx.x * 4;
    float gg = lng[t], bbv = lnb[t];
    float acc = 0.f;
    for (int i = 0; i < 4; ++i) {
        size_t r = r0 + i;
        float v = x[r * 256 + t];
        float s = v, q = v * v;
        for (int o = 32; o > 0; o >>= 1) { s += __shfl_xor(s, o, 64); q += __shfl_xor(q, o, 64); }
        if ((t & 63) == 0) { red[t >> 6] = s; red[4 + (t >> 6)] = q; }
        __syncthreads();
        if (t == 0) {
            float S = red[0] + red[1] + red[2] + red[3];
            float Q = red[4] + red[5] + red[6] + red[7];
            float mu = S * (1.f / 256.f);
            mv[0] = mu;
            mv[1] = rsqrtf(Q * (1.f / 256.f) - mu * mu + 1e-5f);
        }
        __syncthreads();
        xn[r * 256 + t] = (__bf16)((v - mv[0]) * mv[1] * gg + bbv);
        acc += v;
        __syncthreads();
    }
    int b = r0 >> 12;
    int g = (r0 & 4095) >> 2;
    skipo[((size_t)b * TOK + g) * 256 + t] = acc * 0.25f;
}

// ---------------------------------------------------------------------------
// MFMA GEMM1: [z|h1|g2] = xn(bf16) @ Wf1^T + bf1.  128x128 tile, BK=32.
// z path fused: adapool over 4 rows (one acc quad) + silu -> zp (f32).
// h1/g2: softplus -> bf16.
// ---------------------------------------------------------------------------
__global__ __launch_bounds__(256) void gemm1_mfma(
    const __bf16* __restrict__ A, const __bf16* __restrict__ Bw, const float* __restrict__ bias,
    float* __restrict__ zp, __bf16* __restrict__ h1x, __bf16* __restrict__ g2x)
{
    __shared__ __align__(16) __bf16 As[4096];
    __shared__ __align__(16) __bf16 Bs[4096];
    int tid = threadIdx.x;
    int lane = tid & 63, wv = tid >> 6;
    int wr = wv >> 1, wc = wv & 1;
    int lm = lane & 15, lq = lane >> 4;
    int m0 = blockIdx.x << 7, n0 = blockIdx.y << 7;

    const __bf16* ga0 = A  + (size_t)(m0 + wv * 32 + lm) * 256 + lq * 8;
    const __bf16* ga1 = ga0 + 16 * 256;
    const __bf16* gb0 = Bw + (size_t)(n0 + wv * 32 + lm) * 256 + lq * 8;
    const __bf16* gb1 = gb0 + 16 * 256;
    __bf16* la0 = &As[(wv * 2    ) * 512];
    __bf16* la1 = &As[(wv * 2 + 1) * 512];
    __bf16* lb0 = &Bs[(wv * 2    ) * 512];
    __bf16* lb1 = &Bs[(wv * 2 + 1) * 512];

    f32x4 acc[4][4];
#pragma unroll
    for (int i = 0; i < 4; ++i)
#pragma unroll
        for (int j = 0; j < 4; ++j) acc[i][j] = 0;

    for (int k0 = 0; k0 < 256; k0 += 32) {
        __syncthreads();
        gl_lds16(ga0 + k0, la0);
        gl_lds16(ga1 + k0, la1);
        gl_lds16(gb0 + k0, lb0);
        gl_lds16(gb1 + k0, lb1);
        __syncthreads();
        bf16x8 af[4], bfr[4];
#pragma unroll
        for (int i = 0; i < 4; ++i)
            af[i] = *(const bf16x8*)&As[(wr * 4 + i) * 512 + lane * 8];
#pragma unroll
        for (int j = 0; j < 4; ++j)
            bfr[j] = *(const bf16x8*)&Bs[(wc * 4 + j) * 512 + lane * 8];
#pragma unroll
        for (int i = 0; i < 4; ++i)
#pragma unroll
            for (int j = 0; j < 4; ++j)
                acc[i][j] = __builtin_amdgcn_mfma_f32_16x16x32_bf16(af[i], bfr[j], acc[i][j], 0, 0, 0);
    }

    int target = blockIdx.y >> 1;  // 0:z 1:h1 2:g2
    if (target == 0) {
        // fused adapool(z)+silu: acc quad (r=0..3) is one pool group
#pragma unroll
        for (int j = 0; j < 4; ++j) {
            int col = n0 + wc * 64 + j * 16 + lm;
            float bv = bias[col];
#pragma unroll
            for (int i = 0; i < 4; ++i) {
                int row0 = m0 + wr * 64 + i * 16 + lq * 4;
                float s = acc[i][j][0] + acc[i][j][1] + acc[i][j][2] + acc[i][j][3];
                float zv = siluf(0.25f * s + bv);
                int b = row0 >> 12, g = (row0 & 4095) >> 2;
                zp[((size_t)b * TOK + g) * 256 + col] = zv;
            }
        }
    } else {
        __bf16* outp = (target == 1) ? h1x : g2x;
#pragma unroll
        for (int j = 0; j < 4; ++j) {
            int col = n0 + wc * 64 + j * 16 + lm;
            float bv = bias[col];
            int cl = col & 255;
#pragma unroll
            for (int i = 0; i < 4; ++i) {
                int row = m0 + wr * 64 + i * 16 + lq * 4;
#pragma unroll
                for (int r = 0; r < 4; ++r) {
                    float v = acc[i][j][r] + bv;
                    outp[(size_t)(row + r) * 256 + cl] = (__bf16)softplusf(v);
                }
            }
        }
    }
}

// ---------------------------------------------------------------------------
// MFMA GEMM2 (per dir): [delta|Bm|Cm|pad] = h(bf16) @ Wf2^T + b2, bf16 out.
// ---------------------------------------------------------------------------
__global__ __launch_bounds__(256) void gemm2_mfma(
    const __bf16* __restrict__ h1x, const __bf16* __restrict__ g2x,
    const __bf16* __restrict__ Wf, const float* __restrict__ bf2,
    const __bf16* __restrict__ Wb, const float* __restrict__ bb2,
    __bf16* __restrict__ dlf, __bf16* __restrict__ dlb,
    __bf16* __restrict__ BmF, __bf16* __restrict__ CmF,
    __bf16* __restrict__ BmB, __bf16* __restrict__ CmB)
{
    __shared__ __align__(16) __bf16 As[4096];
    __shared__ __align__(16) __bf16 Bs[4096];
    int tid = threadIdx.x;
    int lane = tid & 63, wv = tid >> 6;
    int wr = wv >> 1, wc = wv & 1;
    int lm = lane & 15, lq = lane >> 4;
    int m0 = blockIdx.x << 7, n0 = blockIdx.y << 7;
    int dir = blockIdx.z;
    const __bf16* A    = dir ? g2x : h1x;
    const __bf16* Bw   = dir ? Wb : Wf;
    const float* bias  = dir ? bb2 : bf2;
    __bf16* dl = dir ? dlb : dlf;
    __bf16* Bm = dir ? BmB : BmF;
    __bf16* Cm = dir ? CmB : CmF;

    const __bf16* ga0 = A  + (size_t)(m0 + wv * 32 + lm) * 256 + lq * 8;
    const __bf16* ga1 = ga0 + 16 * 256;
    const __bf16* gb0 = Bw + (size_t)(n0 + wv * 32 + lm) * 256 + lq * 8;
    const __bf16* gb1 = gb0 + 16 * 256;
    __bf16* la0 = &As[(wv * 2    ) * 512];
    __bf16* la1 = &As[(wv * 2 + 1) * 512];
    __bf16* lb0 = &Bs[(wv * 2    ) * 512];
    __bf16* lb1 = &Bs[(wv * 2 + 1) * 512];

    f32x4 acc[4][4];
#pragma unroll
    for (int i = 0; i < 4; ++i)
#pragma unroll
        for (int j = 0; j < 4; ++j) acc[i][j] = 0;

    for (int k0 = 0; k0 < 256; k0 += 32) {
        __syncthreads();
        gl_lds16(ga0 + k0, la0);
        gl_lds16(ga1 + k0, la1);
        gl_lds16(gb0 + k0, lb0);
        gl_lds16(gb1 + k0, lb1);
        __syncthreads();
        bf16x8 af[4], bfr[4];
#pragma unroll
        for (int i = 0; i < 4; ++i)
            af[i] = *(const bf16x8*)&As[(wr * 4 + i) * 512 + lane * 8];
#pragma unroll
        for (int j = 0; j < 4; ++j)
            bfr[j] = *(const bf16x8*)&Bs[(wc * 4 + j) * 512 + lane * 8];
#pragma unroll
        for (int i = 0; i < 4; ++i)
#pragma unroll
            for (int j = 0; j < 4; ++j)
                acc[i][j] = __builtin_amdgcn_mfma_f32_16x16x32_bf16(af[i], bfr[j], acc[i][j], 0, 0, 0);
    }

#pragma unroll
    for (int j = 0; j < 4; ++j) {
        int col = n0 + wc * 64 + j * 16 + lm;
        if (col >= 288) continue;
        float bv = bias[col];
#pragma unroll
        for (int i = 0; i < 4; ++i) {
            int row = m0 + wr * 64 + i * 16 + lq * 4;
#pragma unroll
            for (int r = 0; r < 4; ++r) {
                float v = acc[i][j][r] + bv;
                size_t rr = (size_t)(row + r);
                if (col < 256)       dl[rr * 256 + col] = (__bf16)softplusf(v);
                else if (col < 272)  Bm[rr * 16 + (col - 256)] = (__bf16)v;
                else                 Cm[rr * 16 + (col - 272)] = (__bf16)v;
            }
        }
    }
}

// ---------------------------------------------------------------------------
// Scan pass 1: one thread per (dir,b,chunk,d); h[16] in registers.
// a_n = exp(-delta)^(n+1) via power chain (A_n == -(n+1), runtime-verified).
// ---------------------------------------------------------------------------
__global__ __launch_bounds__(256) void scan1_kernel(
    const __bf16* __restrict__ df, const __bf16* __restrict__ db,
    const __bf16* __restrict__ xf, const __bf16* __restrict__ xb,
    const __bf16* __restrict__ bmf, const __bf16* __restrict__ bmb,
    const float* __restrict__ alogf, const float* __restrict__ alogb,
    float* __restrict__ aprod, float* __restrict__ hend)
{
    int d = threadIdx.x;
    int c = blockIdx.x, b = blockIdx.y, dir = blockIdx.z;
    const __bf16* delta = dir ? db : df;
    const __bf16* xin   = dir ? xb : xf;
    const __bf16* Bm    = dir ? bmb : bmf;
    const float* Alog   = dir ? alogb : alogf;

    float A[16];
    bool intOK = true;
#pragma unroll
    for (int n = 0; n < 16; ++n) {
        A[n] = -__expf(Alog[(size_t)d * 16 + n]);
        intOK = intOK && (fabsf(A[n] + (float)(n + 1)) < 1e-3f);
    }
    float h[16];
#pragma unroll
    for (int n = 0; n < 16; ++n) h[n] = 0.f;
    float sd = 0.f;
    int base = c * CLEN;
    if (intOK) {
        for (int it = 0; it < CLEN; ++it) {
            int t = dir ? (base + CLEN - 1 - it) : (base + it);
            size_t row = (size_t)b * LL + t;
            float dlt = (float)delta[row * DD + d];
            float xv  = (float)xin[row * DD + d];
            float common = dlt * xv;
            sd += dlt;
            float p[16];
            pow_chain(__expf(-dlt), p);
            const bf16x8* Bp = (const bf16x8*)&Bm[row * NS];
            bf16x8 b0 = Bp[0], b1 = Bp[1];
#pragma unroll
            for (int n = 0; n < 8; ++n) {
                h[n]     = fmaf(p[n],     h[n],     common * (float)b0[n]);
                h[n + 8] = fmaf(p[n + 8], h[n + 8], common * (float)b1[n]);
            }
        }
        float pe[16];
        pow_chain(__expf(-sd), pe);
        size_t idx = ((((size_t)dir * BB + b) * DD + d) * NCH + c) * NS;
#pragma unroll
        for (int q = 0; q < 4; ++q) {
            float4 av, hv;
            av.x = pe[q * 4 + 0]; av.y = pe[q * 4 + 1]; av.z = pe[q * 4 + 2]; av.w = pe[q * 4 + 3];
            hv.x = h[q * 4 + 0];  hv.y = h[q * 4 + 1];  hv.z = h[q * 4 + 2];  hv.w = h[q * 4 + 3];
            *(float4*)&aprod[idx + q * 4] = av;
            *(float4*)&hend[idx + q * 4] = hv;
        }
    } else {
        for (int it = 0; it < CLEN; ++it) {
            int t = dir ? (base + CLEN - 1 - it) : (base + it);
            size_t row = (size_t)b * LL + t;
            float dlt = (float)delta[row * DD + d];
            float xv  = (float)xin[row * DD + d];
            float common = dlt * xv;
            sd += dlt;
            const bf16x8* Bp = (const bf16x8*)&Bm[row * NS];
            bf16x8 b0 = Bp[0], b1 = Bp[1];
#pragma unroll
            for (int n = 0; n < 8; ++n) {
                h[n]     = fmaf(__expf(dlt * A[n]),     h[n],     common * (float)b0[n]);
                h[n + 8] = fmaf(__expf(dlt * A[n + 8]), h[n + 8], common * (float)b1[n]);
            }
        }
        size_t idx = ((((size_t)dir * BB + b) * DD + d) * NCH + c) * NS;
#pragma unroll
        for (int n = 0; n < 16; ++n) {
            aprod[idx + n] = __expf(sd * A[n]);
            hend[idx + n] = h[n];
        }
    }
}

// ---------------------------------------------------------------------------
// Scan pass 2: chain the 64 chunk aggregates; in place hend -> hin.
// ---------------------------------------------------------------------------
__global__ __launch_bounds__(256) void scan2_kernel(
    const float* __restrict__ aprod, float* __restrict__ hh)
{
    int g = blockIdx.x * 256 + threadIdx.x;
    int n = g & 15, d = (g >> 4) & 255, b = (g >> 12) & 3, dir = (g >> 14) & 1;
    size_t bidx = (((size_t)dir * BB + b) * DD + d) * NCH;
    float s = 0.f;
    if (!dir) {
        for (int c = 0; c < NCH; ++c) {
            size_t idx = (bidx + c) * NS + n;
            float a = aprod[idx], he = hh[idx];
            hh[idx] = s;
            s = fmaf(a, s, he);
        }
    } else {
        for (int c = NCH - 1; c >= 0; --c) {
            size_t idx = (bidx + c) * NS + n;
            float a = aprod[idx], he = hh[idx];
            hh[idx] = s;
            s = fmaf(a, s, he);
        }
    }
}

// ---------------------------------------------------------------------------
// Scan pass 3: replay with true prefix; pooled y only.
// ---------------------------------------------------------------------------
__global__ __launch_bounds__(256) void scan3_kernel(
    const __bf16* __restrict__ df, const __bf16* __restrict__ db,
    const __bf16* __restrict__ xf, const __bf16* __restrict__ xb,
    const __bf16* __restrict__ bmf, const __bf16* __restrict__ bmb,
    const __bf16* __restrict__ cmf, const __bf16* __restrict__ cmb,
    const float* __restrict__ alogf, const float* __restrict__ alogb,
    const float* __restrict__ Dfp, const float* __restrict__ Dbp,
    const float* __restrict__ hin,
    float* __restrict__ y1, float* __restrict__ y2)
{
    int d = threadIdx.x;
    int c = blockIdx.x, b = blockIdx.y, dir = blockIdx.z;
    const __bf16* delta = dir ? db : df;
    const __bf16* xin   = dir ? xb : xf;
    const __bf16* Bm    = dir ? bmb : bmf;
    const __bf16* Cm    = dir ? cmb : cmf;
    const float* Alog   = dir ? alogb : alogf;
    const float* Dv     = dir ? Dbp : Dfp;
    float* yout = dir ? y2 : y1;

    float A[16];
    bool intOK = true;
#pragma unroll
    for (int n = 0; n < 16; ++n) {
        A[n] = -__expf(Alog[(size_t)d * 16 + n]);
        intOK = intOK && (fabsf(A[n] + (float)(n + 1)) < 1e-3f);
    }
    float Dd = Dv[d];
    float h[16];
    size_t idx = ((((size_t)dir * BB + b) * DD + d) * NCH + c) * NS;
#pragma unroll
    for (int q = 0; q < 4; ++q) {
        float4 hv = *(const float4*)&hin[idx + q * 4];
        h[q * 4 + 0] = hv.x; h[q * 4 + 1] = hv.y; h[q * 4 + 2] = hv.z; h[q * 4 + 3] = hv.w;
    }
    int base = c * CLEN;
    float pool = 0.f;
    if (intOK) {
        for (int it = 0; it < CLEN; ++it) {
            int t = dir ? (base + CLEN - 1 - it) : (base + it);
            size_t row = (size_t)b * LL + t;
            float dlt = (float)delta[row * DD + d];
            float xv  = (float)xin[row * DD + d];
            float common = dlt * xv;
            float p[16];
            pow_chain(__expf(-dlt), p);
            const bf16x8* Bp = (const bf16x8*)&Bm[row * NS];
            const bf16x8* Cp = (const bf16x8*)&Cm[row * NS];
            bf16x8 b0 = Bp[0], b1 = Bp[1];
            bf16x8 c0 = Cp[0], c1 = Cp[1];
            float yac = 0.f;
#pragma unroll
            for (int n = 0; n < 8; ++n) {
                h[n]     = fmaf(p[n],     h[n],     common * (float)b0[n]);
                h[n + 8] = fmaf(p[n + 8], h[n + 8], common * (float)b1[n]);
                yac = fmaf(h[n], (float)c0[n], yac);
                yac = fmaf(h[n + 8], (float)c1[n], yac);
            }
            pool += yac + Dd * xv;
            bool gend = dir ? ((t & 3) == 0) : ((t & 3) == 3);
            if (gend) {
                yout[((size_t)b * TOK + (t >> 2)) * DD + d] = pool * 0.25f;
                pool = 0.f;
            }
        }
    } else {
        for (int it = 0; it < CLEN; ++it) {
            int t = dir ? (base + CLEN - 1 - it) : (base + it);
            size_t row = (size_t)b * LL + t;
            float dlt = (float)delta[row * DD + d];
            float xv  = (float)xin[row * DD + d];
            float common = dlt * xv;
            const bf16x8* Bp = (const bf16x8*)&Bm[row * NS];
            const bf16x8* Cp = (const bf16x8*)&Cm[row * NS];
            bf16x8 b0 = Bp[0], b1 = Bp[1];
            bf16x8 c0 = Cp[0], c1 = Cp[1];
            float yac = 0.f;
#pragma unroll
            for (int n = 0; n < 8; ++n) {
                h[n]     = fmaf(__expf(dlt * A[n]),     h[n],     common * (float)b0[n]);
                h[n + 8] = fmaf(__expf(dlt * A[n + 8]), h[n + 8], common * (float)b1[n]);
                yac = fmaf(h[n], (float)c0[n], yac);
                yac = fmaf(h[n + 8], (float)c1[n], yac);
            }
            pool += yac + Dd * xv;
            bool gend = dir ? ((t & 3) == 0) : ((t & 3) == 3);
            if (gend) {
                yout[((size_t)b * TOK + (t >> 2)) * DD + d] = pool * 0.25f;
                pool = 0.f;
            }
        }
    }
}

// ---------------------------------------------------------------------------
// Final: out = zp*(silu(y1*mask)+silu(y2*mask)) + skip
// ---------------------------------------------------------------------------
__global__ __launch_bounds__(256) void final_kernel(
    const float* __restrict__ zp, const float* __restrict__ y1, const float* __restrict__ y2,
    const float* __restrict__ mask, const float* __restrict__ skipi, float* __restrict__ out)
{
    int p = blockIdx.x;
    int g = p & 1023;
    int d = threadIdx.x;
    size_t ip = (size_t)p * 256 + d;
    float mk = mask[g];
    float a1 = y1[ip] * mk, a2 = y2[ip] * mk;
    out[ip] = zp[ip] * (siluf(a1) + siluf(a2)) + skipi[ip];
}

// ---------------------------------------------------------------------------
extern "C" void kernel_launch(void* const* d_in, const int* in_sizes, int n_in,
                              void* d_out, int out_size, void* d_ws, size_t ws_size,
                              hipStream_t stream)
{
    const float* x      = (const float*)d_in[0];
    const float* ln_g   = (const float*)d_in[1];
    const float* ln_b   = (const float*)d_in[2];
    const float* W1     = (const float*)d_in[3];
    const float* b1     = (const float*)d_in[4];
    const float* W2     = (const float*)d_in[5];
    const float* b2     = (const float*)d_in[6];
    const float* Wcf    = (const float*)d_in[7];
    const float* bcf    = (const float*)d_in[8];
    const float* Wcb    = (const float*)d_in[9];
    const float* bcb    = (const float*)d_in[10];
    const float* Wdbc_f = (const float*)d_in[11];
    const float* Wdt_f  = (const float*)d_in[12];
    const float* bdt_f  = (const float*)d_in[13];
    const float* Alog_f = (const float*)d_in[14];
    const float* D_f    = (const float*)d_in[15];
    const float* Wdbc_b = (const float*)d_in[16];
    const float* Wdt_b  = (const float*)d_in[17];
    const float* bdt_b  = (const float*)d_in[18];
    const float* Alog_b = (const float*)d_in[19];
    const float* D_b    = (const float*)d_in[20];
    float* out = (float*)d_out;
    float* ws  = (float*)d_ws;

    __bf16* xnb = (__bf16*)(ws + O_XN);
    __bf16* dlf = (__bf16*)(ws + O_DLF);   // aliases xnb (dead after gemm1)
    __bf16* dlb = (__bf16*)(ws + O_DLB);
    __bf16* h1x = (__bf16*)(ws + O_H1X);
    __bf16* g2x = (__bf16*)(ws + O_G2X);
    __bf16* bmf = (__bf16*)(ws + O_BMF);
    __bf16* cmf = (__bf16*)(ws + O_CMF);
    __bf16* bmb = (__bf16*)(ws + O_BMB);
    __bf16* cmb = (__bf16*)(ws + O_CMB);
    float* zpb  = ws + O_ZP;
    float* skb  = ws + O_SKIP;
    float* y1b  = ws + O_Y1;
    float* y2b  = ws + O_Y2;
    __bf16* wf1 = (__bf16*)(ws + O_WF1);
    float* bf1  = ws + O_BF1;
    __bf16* wf2f = (__bf16*)(ws + O_WF2F);
    float* b2f  = ws + O_B2F;
    __bf16* wf2b = (__bf16*)(ws + O_WF2B);
    float* b2b  = ws + O_B2B;
    float* apr  = ws + O_APROD;
    float* hnd  = ws + O_HEND;   // hend, then hin in place
    float* mkb  = ws + O_MASK;

    prep_wc_kernel<<<dim3(256, 2), 256, 0, stream>>>(W1, b1, W2, b2, Wcf, bcf, Wcb, bcb, wf1, bf1);
    prep_wdd_kernel<<<dim3(384, 2), 256, 0, stream>>>(Wdt_f, Wdbc_f, bdt_f, Wdt_b, Wdbc_b, bdt_b,
                                                      wf2f, b2f, wf2b, b2b);
    mask_kernel<<<1, 1024, 0, stream>>>(mkb);
    ln_kernel<<<4096, 256, 0, stream>>>(x, ln_g, ln_b, xnb, skb);
    gemm1_mfma<<<dim3(128, 6), 256, 0, stream>>>(xnb, wf1, bf1, zpb, h1x, g2x);
    gemm2_mfma<<<dim3(128, 3, 2), 256, 0, stream>>>(h1x, g2x, wf2f, b2f, wf2b, b2b,
                                                    dlf, dlb, bmf, cmf, bmb, cmb);
    scan1_kernel<<<dim3(NCH, BB, 2), 256, 0, stream>>>(dlf, dlb, h1x, g2x, bmf, bmb,
                                                       Alog_f, Alog_b, apr, hnd);
    scan2_kernel<<<128, 256, 0, stream>>>(apr, hnd);
    scan3_kernel<<<dim3(NCH, BB, 2), 256, 0, stream>>>(dlf, dlb, h1x, g2x, bmf, bmb, cmf, cmb,
                                                       Alog_f, Alog_b, D_f, D_b, hnd, y1b, y2b);
    final_kernel<<<4096, 256, 0, stream>>>(zpb, y1b, y2b, mkb, skb, out);
}

// Round 5
// 243.021 us; speedup vs baseline: 2.7320x; 1.0377x over previous
//
#include <hip/hip_runtime.h>
#include <math.h>

// ---------------------------------------------------------------------------
// VisionEncoderMambaBlock  (B=4, L=4096, D=256, d_state=16, T=1024)
// Round 4:
//  - LDS-staged coalesced epilogues in gemm1/gemm2 (256B+ store segments
//    instead of 32B scatter; Bm/Cm dumped as contiguous 4KB tiles)
//  - scan2 unrolled x8 (batch the 64-step L2-latency chain loads)
//  - prep_wc + prep_wdd + mask merged into one launch (8 dispatches total)
// ---------------------------------------------------------------------------

namespace {
constexpr int BB = 4;
constexpr int LL = 4096;
constexpr int DD = 256;
constexpr int NS = 16;       // d_state
constexpr int NCH = 64;
constexpr int CLEN = 64;     // LL / NCH
constexpr int TOK = 1024;

constexpr size_t NROW = (size_t)BB * LL;   // 16384
constexpr size_t NE   = NROW * DD;         // 4,194,304
constexpr size_t NP   = (size_t)BB * TOK * DD; // 1,048,576
constexpr size_t NBC  = NROW * NS;         // 262,144
constexpr size_t NAGG = 2ull * BB * DD * NCH * NS; // 4,194,304

// ws layout (float offsets). bf16 buffers use half their element count.
constexpr size_t O_XN   = 0;                    // xn bf16; later dlf bf16
constexpr size_t O_DLF  = O_XN;                 // alias (xn dead after gemm1)
constexpr size_t O_DLB  = NE / 2;               // delta_b bf16
constexpr size_t O_H1X  = NE;                   // h1 bf16
constexpr size_t O_G2X  = NE + NE / 2;          // g2 bf16
constexpr size_t O_BMF  = 2 * NE;               // bf16 NBC
constexpr size_t O_CMF  = O_BMF + NBC / 2;
constexpr size_t O_BMB  = O_CMF + NBC / 2;
constexpr size_t O_CMB  = O_BMB + NBC / 2;
constexpr size_t O_ZP   = O_CMB + NBC / 2;      // zp f32 (B,TOK,D)
constexpr size_t O_SKIP = O_ZP + NP;
constexpr size_t O_Y1   = O_SKIP + NP;
constexpr size_t O_Y2   = O_Y1 + NP;
constexpr size_t O_WF1  = O_Y2 + NP;            // 768x256 bf16
constexpr size_t O_BF1  = O_WF1 + 768 * 256 / 2;
constexpr size_t O_WF2F = O_BF1 + 768;          // 384x256 bf16
constexpr size_t O_B2F  = O_WF2F + 384 * 256 / 2;
constexpr size_t O_WF2B = O_B2F + 384;
constexpr size_t O_B2B  = O_WF2B + 384 * 256 / 2;
constexpr size_t O_APROD = O_B2B + 384;         // f32 NAGG
constexpr size_t O_HEND = O_APROD + NAGG;       // f32 NAGG; hin in place
constexpr size_t O_MASK = O_HEND + NAGG;        // 1024

constexpr int SSTRIDE = 136;  // bf16 stage row stride (272B, 16B-aligned)
} // namespace

typedef __bf16 bf16x8 __attribute__((ext_vector_type(8)));
typedef float f32x4 __attribute__((ext_vector_type(4)));

__device__ __forceinline__ float softplusf(float x) {
    return fmaxf(x, 0.f) + __logf(1.f + __expf(-fabsf(x)));
}
__device__ __forceinline__ float siluf(float x) {
    return x / (1.f + __expf(-x));
}
__device__ __forceinline__ void gl_lds16(const void* g, void* l) {
    __builtin_amdgcn_global_load_lds((const __attribute__((address_space(1))) unsigned int*)g,
                                     (__attribute__((address_space(3))) unsigned int*)l, 16, 0, 0);
}
// p[n] = e1^(n+1), log-depth-4 chain (15 muls)
__device__ __forceinline__ void pow_chain(float e1, float* p) {
    p[0] = e1;
    p[1] = e1 * e1;
    p[2] = p[1] * e1;
    p[3] = p[1] * p[1];
    p[4] = p[3] * p[0];
    p[5] = p[3] * p[1];
    p[6] = p[3] * p[2];
    p[7] = p[3] * p[3];
    p[8]  = p[7] * p[0];
    p[9]  = p[7] * p[1];
    p[10] = p[7] * p[2];
    p[11] = p[7] * p[3];
    p[12] = p[7] * p[4];
    p[13] = p[7] * p[5];
    p[14] = p[7] * p[6];
    p[15] = p[7] * p[7];
}

// ---------------------------------------------------------------------------
// Fused prep: bx<256 -> Wf1 rows; 256<=bx<640 -> Wf2 rows; bx==640 -> mask.
// grid (641, 2) x 256.
// ---------------------------------------------------------------------------
__global__ __launch_bounds__(256) void prep_all_kernel(
    const float* __restrict__ W1, const float* __restrict__ b1,
    const float* __restrict__ W2, const float* __restrict__ b2,
    const float* __restrict__ Wcf, const float* __restrict__ bcf,
    const float* __restrict__ Wcb, const float* __restrict__ bcb,
    const float* __restrict__ Wdt_f, const float* __restrict__ Wdbc_f, const float* __restrict__ bdt_f,
    const float* __restrict__ Wdt_b, const float* __restrict__ Wdbc_b, const float* __restrict__ bdt_b,
    __bf16* __restrict__ Wf1, float* __restrict__ bf1,
    __bf16* __restrict__ Wf2f, float* __restrict__ b2f,
    __bf16* __restrict__ Wf2b, float* __restrict__ b2b,
    float* __restrict__ mask)
{
    int bx = blockIdx.x, mat = blockIdx.y, k = threadIdx.x;
    if (bx < 256) {
        int j = bx;
        const float* Wc = mat ? Wcb : Wcf;
        float acc = 0.f, accb = 0.f;
        for (int m = 0; m < 256; ++m) {
            float w = Wc[j * 256 + m];
            acc  = fmaf(w, W2[m * 256 + k], acc);
            accb = fmaf(w, b2[m], accb);
        }
        Wf1[(size_t)(256 + mat * 256 + j) * 256 + k] = (__bf16)acc;
        if (k == 0) bf1[256 + mat * 256 + j] = accb + (mat ? bcb[j] : bcf[j]);
        if (mat == 0) {
            Wf1[(size_t)j * 256 + k] = (__bf16)W1[j * 256 + k];
            if (k == 0) bf1[j] = b1[j];
        }
    } else if (bx < 640) {
        int j = bx - 256;
        const float* Wdt  = mat ? Wdt_b : Wdt_f;
        const float* Wdbc = mat ? Wdbc_b : Wdbc_f;
        const float* bdt  = mat ? bdt_b : bdt_f;
        __bf16* Wf2 = mat ? Wf2b : Wf2f;
        float* b2x  = mat ? b2b : b2f;
        float val;
        if (j < 256) {
            float acc = 0.f;
#pragma unroll
            for (int m = 0; m < 16; ++m)
                acc = fmaf(Wdt[j * 16 + m], Wdbc[m * 256 + k], acc);
            val = acc;
        } else if (j < 288) {
            val = Wdbc[(16 + (j - 256)) * 256 + k];
        } else {
            val = 0.f;
        }
        Wf2[(size_t)j * 256 + k] = (__bf16)val;
        if (k == 0) b2x[j] = (j < 256) ? bdt[j] : 0.f;
    } else if (mat == 0) {
        // Gaussian mask, T=1024. sigma = mean|i-512| = 256 exactly.
        __shared__ float red[4];
        __shared__ float sb;
        float w[4];
        float loc = 0.f;
#pragma unroll
        for (int q = 0; q < 4; ++q) {
            float dd = (float)(k + 256 * q) - 512.f;
            w[q] = __expf(-0.5f * dd * dd * (1.f / 65536.f));
            loc += w[q];
        }
        for (int o = 32; o > 0; o >>= 1) loc += __shfl_xor(loc, o, 64);
        if ((k & 63) == 0) red[k >> 6] = loc;
        __syncthreads();
        if (k == 0) sb = red[0] + red[1] + red[2] + red[3];
        __syncthreads();
        float inv = 1.f / sb;
#pragma unroll
        for (int q = 0; q < 4; ++q) mask[k + 256 * q] = w[q] * inv;
    }
}

// ---------------------------------------------------------------------------
// LayerNorm (bf16 out) + skip adapool.
// ---------------------------------------------------------------------------
__global__ __launch_bounds__(256) void ln_kernel(
    const float* __restrict__ x, const float* __restrict__ lng, const float* __restrict__ lnb,
    __bf16* __restrict__ xn, float* __restrict__ skipo)
{
    __shared__ float red[8];
    __shared__ float mv[2];
    int t = threadIdx.x;
    int r0 = blockIdx.x * 4;
    float gg = lng[t], bbv = lnb[t];
    float acc = 0.f;
    for (int i = 0; i < 4; ++i) {
        size_t r = r0 + i;
        float v = x[r * 256 + t];
        float s = v, q = v * v;
        for (int o = 32; o > 0; o >>= 1) { s += __shfl_xor(s, o, 64); q += __shfl_xor(q, o, 64); }
        if ((t & 63) == 0) { red[t >> 6] = s; red[4 + (t >> 6)] = q; }
        __syncthreads();
        if (t == 0) {
            float S = red[0] + red[1] + red[2] + red[3];
            float Q = red[4] + red[5] + red[6] + red[7];
            float mu = S * (1.f / 256.f);
            mv[0] = mu;
            mv[1] = rsqrtf(Q * (1.f / 256.f) - mu * mu + 1e-5f);
        }
        __syncthreads();
        xn[r * 256 + t] = (__bf16)((v - mv[0]) * mv[1] * gg + bbv);
        acc += v;
        __syncthreads();
    }
    int b = r0 >> 12;
    int g = (r0 & 4095) >> 2;
    skipo[((size_t)b * TOK + g) * 256 + t] = acc * 0.25f;
}

// ---------------------------------------------------------------------------
// MFMA GEMM1: [z|h1|g2] = xn(bf16) @ Wf1^T + bf1.  128x128 tile, BK=32.
// Epilogue staged through LDS for coalesced stores:
//   z: adapool+silu -> zp f32 (32x128 tile, 512B row segments)
//   h1/g2: softplus -> bf16 (128x128 tile, 256B row segments)
// ---------------------------------------------------------------------------
__global__ __launch_bounds__(256) void gemm1_mfma(
    const __bf16* __restrict__ A, const __bf16* __restrict__ Bw, const float* __restrict__ bias,
    float* __restrict__ zp, __bf16* __restrict__ h1x, __bf16* __restrict__ g2x)
{
    __shared__ __align__(16) __bf16 As[4096];
    __shared__ __align__(16) __bf16 Bs[4096];
    __shared__ __align__(16) unsigned char Stage[128 * SSTRIDE * 2]; // 34816B
    int tid = threadIdx.x;
    int lane = tid & 63, wv = tid >> 6;
    int wr = wv >> 1, wc = wv & 1;
    int lm = lane & 15, lq = lane >> 4;
    int m0 = blockIdx.x << 7, n0 = blockIdx.y << 7;

    const __bf16* ga0 = A  + (size_t)(m0 + wv * 32 + lm) * 256 + lq * 8;
    const __bf16* ga1 = ga0 + 16 * 256;
    const __bf16* gb0 = Bw + (size_t)(n0 + wv * 32 + lm) * 256 + lq * 8;
    const __bf16* gb1 = gb0 + 16 * 256;
    __bf16* la0 = &As[(wv * 2    ) * 512];
    __bf16* la1 = &As[(wv * 2 + 1) * 512];
    __bf16* lb0 = &Bs[(wv * 2    ) * 512];
    __bf16* lb1 = &Bs[(wv * 2 + 1) * 512];

    f32x4 acc[4][4];
#pragma unroll
    for (int i = 0; i < 4; ++i)
#pragma unroll
        for (int j = 0; j < 4; ++j) acc[i][j] = 0;

    for (int k0 = 0; k0 < 256; k0 += 32) {
        __syncthreads();
        gl_lds16(ga0 + k0, la0);
        gl_lds16(ga1 + k0, la1);
        gl_lds16(gb0 + k0, lb0);
        gl_lds16(gb1 + k0, lb1);
        __syncthreads();
        bf16x8 af[4], bfr[4];
#pragma unroll
        for (int i = 0; i < 4; ++i)
            af[i] = *(const bf16x8*)&As[(wr * 4 + i) * 512 + lane * 8];
#pragma unroll
        for (int j = 0; j < 4; ++j)
            bfr[j] = *(const bf16x8*)&Bs[(wc * 4 + j) * 512 + lane * 8];
#pragma unroll
        for (int i = 0; i < 4; ++i)
#pragma unroll
            for (int j = 0; j < 4; ++j)
                acc[i][j] = __builtin_amdgcn_mfma_f32_16x16x32_bf16(af[i], bfr[j], acc[i][j], 0, 0, 0);
    }

    int target = blockIdx.y >> 1;  // 0:z 1:h1 2:g2
    int colbase = (blockIdx.y & 1) * 128;
    __syncthreads();
    if (target == 0) {
        // fused adapool(z)+silu staged as 32 groups x 128 cols f32 (stride 132)
        float* zs = (float*)Stage;
#pragma unroll
        for (int j = 0; j < 4; ++j) {
            int coll = wc * 64 + j * 16 + lm;
            float bv = bias[n0 + coll];
#pragma unroll
            for (int i = 0; i < 4; ++i) {
                int gl = wr * 16 + i * 4 + lq;
                float s = acc[i][j][0] + acc[i][j][1] + acc[i][j][2] + acc[i][j][3];
                zs[gl * 132 + coll] = siluf(0.25f * s + bv);
            }
        }
        __syncthreads();
        int b = m0 >> 12, g0 = (m0 & 4095) >> 2;
        int rl = tid >> 5;
        int c4 = (tid & 31) * 4;
#pragma unroll
        for (int p = 0; p < 4; ++p) {
            int g = p * 8 + rl;
            float4 v = *(float4*)&zs[g * 132 + c4];
            *(float4*)&zp[((size_t)b * TOK + g0 + g) * 256 + colbase + c4] = v;
        }
    } else {
        __bf16* hs = (__bf16*)Stage; // 128 x SSTRIDE
#pragma unroll
        for (int j = 0; j < 4; ++j) {
            int coll = wc * 64 + j * 16 + lm;
            float bv = bias[n0 + coll];
#pragma unroll
            for (int i = 0; i < 4; ++i) {
                int rl = wr * 64 + i * 16 + lq * 4;
#pragma unroll
                for (int r = 0; r < 4; ++r)
                    hs[(rl + r) * SSTRIDE + coll] = (__bf16)softplusf(acc[i][j][r] + bv);
            }
        }
        __syncthreads();
        __bf16* outp = (target == 1) ? h1x : g2x;
        int rl = tid >> 4;
        int c8 = (tid & 15) * 8;
#pragma unroll
        for (int p = 0; p < 8; ++p) {
            int row = p * 16 + rl;
            bf16x8 v = *(bf16x8*)&hs[row * SSTRIDE + c8];
            *(bf16x8*)&outp[(size_t)(m0 + row) * 256 + colbase + c8] = v;
        }
    }
}

// ---------------------------------------------------------------------------
// MFMA GEMM2 (per dir): [delta|Bm|Cm|pad] = h(bf16) @ Wf2^T + b2, bf16 out.
// Tiles 0,1: softplus->dl (LDS-staged, coalesced). Tile 2: Bm/Cm staged and
// dumped as fully-contiguous 4KB tiles.
// ---------------------------------------------------------------------------
__global__ __launch_bounds__(256) void gemm2_mfma(
    const __bf16* __restrict__ h1x, const __bf16* __restrict__ g2x,
    const __bf16* __restrict__ Wf, const float* __restrict__ bf2,
    const __bf16* __restrict__ Wb, const float* __restrict__ bb2,
    __bf16* __restrict__ dlf, __bf16* __restrict__ dlb,
    __bf16* __restrict__ BmF, __bf16* __restrict__ CmF,
    __bf16* __restrict__ BmB, __bf16* __restrict__ CmB)
{
    __shared__ __align__(16) __bf16 As[4096];
    __shared__ __align__(16) __bf16 Bs[4096];
    __shared__ __align__(16) unsigned char Stage[128 * SSTRIDE * 2];
    int tid = threadIdx.x;
    int lane = tid & 63, wv = tid >> 6;
    int wr = wv >> 1, wc = wv & 1;
    int lm = lane & 15, lq = lane >> 4;
    int m0 = blockIdx.x << 7, n0 = blockIdx.y << 7;
    int dir = blockIdx.z;
    const __bf16* A    = dir ? g2x : h1x;
    const __bf16* Bw   = dir ? Wb : Wf;
    const float* bias  = dir ? bb2 : bf2;
    __bf16* dl = dir ? dlb : dlf;
    __bf16* Bm = dir ? BmB : BmF;
    __bf16* Cm = dir ? CmB : CmF;

    const __bf16* ga0 = A  + (size_t)(m0 + wv * 32 + lm) * 256 + lq * 8;
    const __bf16* ga1 = ga0 + 16 * 256;
    const __bf16* gb0 = Bw + (size_t)(n0 + wv * 32 + lm) * 256 + lq * 8;
    const __bf16* gb1 = gb0 + 16 * 256;
    __bf16* la0 = &As[(wv * 2    ) * 512];
    __bf16* la1 = &As[(wv * 2 + 1) * 512];
    __bf16* lb0 = &Bs[(wv * 2    ) * 512];
    __bf16* lb1 = &Bs[(wv * 2 + 1) * 512];

    f32x4 acc[4][4];
#pragma unroll
    for (int i = 0; i < 4; ++i)
#pragma unroll
        for (int j = 0; j < 4; ++j) acc[i][j] = 0;

    for (int k0 = 0; k0 < 256; k0 += 32) {
        __syncthreads();
        gl_lds16(ga0 + k0, la0);
        gl_lds16(ga1 + k0, la1);
        gl_lds16(gb0 + k0, lb0);
        gl_lds16(gb1 + k0, lb1);
        __syncthreads();
        bf16x8 af[4], bfr[4];
#pragma unroll
        for (int i = 0; i < 4; ++i)
            af[i] = *(const bf16x8*)&As[(wr * 4 + i) * 512 + lane * 8];
#pragma unroll
        for (int j = 0; j < 4; ++j)
            bfr[j] = *(const bf16x8*)&Bs[(wc * 4 + j) * 512 + lane * 8];
#pragma unroll
        for (int i = 0; i < 4; ++i)
#pragma unroll
            for (int j = 0; j < 4; ++j)
                acc[i][j] = __builtin_amdgcn_mfma_f32_16x16x32_bf16(af[i], bfr[j], acc[i][j], 0, 0, 0);
    }

    __syncthreads();
    if (blockIdx.y < 2) {
        // delta tile: softplus -> bf16, staged
        __bf16* hs = (__bf16*)Stage;
        int colbase = (blockIdx.y & 1) * 128;
#pragma unroll
        for (int j = 0; j < 4; ++j) {
            int coll = wc * 64 + j * 16 + lm;
            float bv = bias[n0 + coll];
#pragma unroll
            for (int i = 0; i < 4; ++i) {
                int rl = wr * 64 + i * 16 + lq * 4;
#pragma unroll
                for (int r = 0; r < 4; ++r)
                    hs[(rl + r) * SSTRIDE + coll] = (__bf16)softplusf(acc[i][j][r] + bv);
            }
        }
        __syncthreads();
        int rl = tid >> 4;
        int c8 = (tid & 15) * 8;
#pragma unroll
        for (int p = 0; p < 8; ++p) {
            int row = p * 16 + rl;
            bf16x8 v = *(bf16x8*)&hs[row * SSTRIDE + c8];
            *(bf16x8*)&dl[(size_t)(m0 + row) * 256 + colbase + c8] = v;
        }
    } else {
        // Bm (cols 256-271), Cm (272-287): stage 128x16 each (stride 24)
        __bf16* bs_ = (__bf16*)Stage;          // 128 x 24
        __bf16* cs_ = (__bf16*)Stage + 128 * 24;
        if (wc == 0) {
#pragma unroll
            for (int j = 0; j < 2; ++j) {
                int coll = j * 16 + lm;      // global col 256+coll
                float bv = bias[n0 + coll];
                __bf16* dst = j ? cs_ : bs_;
#pragma unroll
                for (int i = 0; i < 4; ++i) {
                    int rl = wr * 64 + i * 16 + lq * 4;
#pragma unroll
                    for (int r = 0; r < 4; ++r)
                        dst[(rl + r) * 24 + lm] = (__bf16)(acc[i][j][r] + bv);
                }
            }
        }
        __syncthreads();
        int row = tid >> 1;
        int c8 = (tid & 1) * 8;
        bf16x8 vb = *(bf16x8*)&bs_[row * 24 + c8];
        bf16x8 vc = *(bf16x8*)&cs_[row * 24 + c8];
        *(bf16x8*)&Bm[(size_t)(m0 + row) * 16 + c8] = vb;
        *(bf16x8*)&Cm[(size_t)(m0 + row) * 16 + c8] = vc;
    }
}

// ---------------------------------------------------------------------------
// Scan pass 1: one thread per (dir,b,chunk,d); h[16] in registers.
// a_n = exp(-delta)^(n+1) via power chain (A_n == -(n+1), runtime-verified).
// ---------------------------------------------------------------------------
__global__ __launch_bounds__(256) void scan1_kernel(
    const __bf16* __restrict__ df, const __bf16* __restrict__ db,
    const __bf16* __restrict__ xf, const __bf16* __restrict__ xb,
    const __bf16* __restrict__ bmf, const __bf16* __restrict__ bmb,
    const float* __restrict__ alogf, const float* __restrict__ alogb,
    float* __restrict__ aprod, float* __restrict__ hend)
{
    int d = threadIdx.x;
    int c = blockIdx.x, b = blockIdx.y, dir = blockIdx.z;
    const __bf16* delta = dir ? db : df;
    const __bf16* xin   = dir ? xb : xf;
    const __bf16* Bm    = dir ? bmb : bmf;
    const float* Alog   = dir ? alogb : alogf;

    float A[16];
    bool intOK = true;
#pragma unroll
    for (int n = 0; n < 16; ++n) {
        A[n] = -__expf(Alog[(size_t)d * 16 + n]);
        intOK = intOK && (fabsf(A[n] + (float)(n + 1)) < 1e-3f);
    }
    float h[16];
#pragma unroll
    for (int n = 0; n < 16; ++n) h[n] = 0.f;
    float sd = 0.f;
    int base = c * CLEN;
    if (intOK) {
        for (int it = 0; it < CLEN; ++it) {
            int t = dir ? (base + CLEN - 1 - it) : (base + it);
            size_t row = (size_t)b * LL + t;
            float dlt = (float)delta[row * DD + d];
            float xv  = (float)xin[row * DD + d];
            float common = dlt * xv;
            sd += dlt;
            float p[16];
            pow_chain(__expf(-dlt), p);
            const bf16x8* Bp = (const bf16x8*)&Bm[row * NS];
            bf16x8 b0 = Bp[0], b1 = Bp[1];
#pragma unroll
            for (int n = 0; n < 8; ++n) {
                h[n]     = fmaf(p[n],     h[n],     common * (float)b0[n]);
                h[n + 8] = fmaf(p[n + 8], h[n + 8], common * (float)b1[n]);
            }
        }
        float pe[16];
        pow_chain(__expf(-sd), pe);
        size_t idx = ((((size_t)dir * BB + b) * DD + d) * NCH + c) * NS;
#pragma unroll
        for (int q = 0; q < 4; ++q) {
            float4 av, hv;
            av.x = pe[q * 4 + 0]; av.y = pe[q * 4 + 1]; av.z = pe[q * 4 + 2]; av.w = pe[q * 4 + 3];
            hv.x = h[q * 4 + 0];  hv.y = h[q * 4 + 1];  hv.z = h[q * 4 + 2];  hv.w = h[q * 4 + 3];
            *(float4*)&aprod[idx + q * 4] = av;
            *(float4*)&hend[idx + q * 4] = hv;
        }
    } else {
        for (int it = 0; it < CLEN; ++it) {
            int t = dir ? (base + CLEN - 1 - it) : (base + it);
            size_t row = (size_t)b * LL + t;
            float dlt = (float)delta[row * DD + d];
            float xv  = (float)xin[row * DD + d];
            float common = dlt * xv;
            sd += dlt;
            const bf16x8* Bp = (const bf16x8*)&Bm[row * NS];
            bf16x8 b0 = Bp[0], b1 = Bp[1];
#pragma unroll
            for (int n = 0; n < 8; ++n) {
                h[n]     = fmaf(__expf(dlt * A[n]),     h[n],     common * (float)b0[n]);
                h[n + 8] = fmaf(__expf(dlt * A[n + 8]), h[n + 8], common * (float)b1[n]);
            }
        }
        size_t idx = ((((size_t)dir * BB + b) * DD + d) * NCH + c) * NS;
#pragma unroll
        for (int n = 0; n < 16; ++n) {
            aprod[idx + n] = __expf(sd * A[n]);
            hend[idx + n] = h[n];
        }
    }
}

// ---------------------------------------------------------------------------
// Scan pass 2: chain the 64 chunk aggregates; in place hend -> hin.
// Unrolled so the compiler can batch the chain's independent loads.
// ---------------------------------------------------------------------------
__global__ __launch_bounds__(256) void scan2_kernel(
    const float* __restrict__ aprod, float* __restrict__ hh)
{
    int g = blockIdx.x * 256 + threadIdx.x;
    int n = g & 15, d = (g >> 4) & 255, b = (g >> 12) & 3, dir = (g >> 14) & 1;
    size_t bidx = (((size_t)dir * BB + b) * DD + d) * NCH;
    float s = 0.f;
    if (!dir) {
#pragma unroll 8
        for (int c = 0; c < NCH; ++c) {
            size_t idx = (bidx + c) * NS + n;
            float a = aprod[idx], he = hh[idx];
            hh[idx] = s;
            s = fmaf(a, s, he);
        }
    } else {
#pragma unroll 8
        for (int c = NCH - 1; c >= 0; --c) {
            size_t idx = (bidx + c) * NS + n;
            float a = aprod[idx], he = hh[idx];
            hh[idx] = s;
            s = fmaf(a, s, he);
        }
    }
}

// ---------------------------------------------------------------------------
// Scan pass 3: replay with true prefix; pooled y only.
// ---------------------------------------------------------------------------
__global__ __launch_bounds__(256) void scan3_kernel(
    const __bf16* __restrict__ df, const __bf16* __restrict__ db,
    const __bf16* __restrict__ xf, const __bf16* __restrict__ xb,
    const __bf16* __restrict__ bmf, const __bf16* __restrict__ bmb,
    const __bf16* __restrict__ cmf, const __bf16* __restrict__ cmb,
    const float* __restrict__ alogf, const float* __restrict__ alogb,
    const float* __restrict__ Dfp, const float* __restrict__ Dbp,
    const float* __restrict__ hin,
    float* __restrict__ y1, float* __restrict__ y2)
{
    int d = threadIdx.x;
    int c = blockIdx.x, b = blockIdx.y, dir = blockIdx.z;
    const __bf16* delta = dir ? db : df;
    const __bf16* xin   = dir ? xb : xf;
    const __bf16* Bm    = dir ? bmb : bmf;
    const __bf16* Cm    = dir ? cmb : cmf;
    const float* Alog   = dir ? alogb : alogf;
    const float* Dv     = dir ? Dbp : Dfp;
    float* yout = dir ? y2 : y1;

    float A[16];
    bool intOK = true;
#pragma unroll
    for (int n = 0; n < 16; ++n) {
        A[n] = -__expf(Alog[(size_t)d * 16 + n]);
        intOK = intOK && (fabsf(A[n] + (float)(n + 1)) < 1e-3f);
    }
    float Dd = Dv[d];
    float h[16];
    size_t idx = ((((size_t)dir * BB + b) * DD + d) * NCH + c) * NS;
#pragma unroll
    for (int q = 0; q < 4; ++q) {
        float4 hv = *(const float4*)&hin[idx + q * 4];
        h[q * 4 + 0] = hv.x; h[q * 4 + 1] = hv.y; h[q * 4 + 2] = hv.z; h[q * 4 + 3] = hv.w;
    }
    int base = c * CLEN;
    float pool = 0.f;
    if (intOK) {
        for (int it = 0; it < CLEN; ++it) {
            int t = dir ? (base + CLEN - 1 - it) : (base + it);
            size_t row = (size_t)b * LL + t;
            float dlt = (float)delta[row * DD + d];
            float xv  = (float)xin[row * DD + d];
            float common = dlt * xv;
            float p[16];
            pow_chain(__expf(-dlt), p);
            const bf16x8* Bp = (const bf16x8*)&Bm[row * NS];
            const bf16x8* Cp = (const bf16x8*)&Cm[row * NS];
            bf16x8 b0 = Bp[0], b1 = Bp[1];
            bf16x8 c0 = Cp[0], c1 = Cp[1];
            float yac = 0.f;
#pragma unroll
            for (int n = 0; n < 8; ++n) {
                h[n]     = fmaf(p[n],     h[n],     common * (float)b0[n]);
                h[n + 8] = fmaf(p[n + 8], h[n + 8], common * (float)b1[n]);
                yac = fmaf(h[n], (float)c0[n], yac);
                yac = fmaf(h[n + 8], (float)c1[n], yac);
            }
            pool += yac + Dd * xv;
            bool gend = dir ? ((t & 3) == 0) : ((t & 3) == 3);
            if (gend) {
                yout[((size_t)b * TOK + (t >> 2)) * DD + d] = pool * 0.25f;
                pool = 0.f;
            }
        }
    } else {
        for (int it = 0; it < CLEN; ++it) {
            int t = dir ? (base + CLEN - 1 - it) : (base + it);
            size_t row = (size_t)b * LL + t;
            float dlt = (float)delta[row * DD + d];
            float xv  = (float)xin[row * DD + d];
            float common = dlt * xv;
            const bf16x8* Bp = (const bf16x8*)&Bm[row * NS];
            const bf16x8* Cp = (const bf16x8*)&Cm[row * NS];
            bf16x8 b0 = Bp[0], b1 = Bp[1];
            bf16x8 c0 = Cp[0], c1 = Cp[1];
            float yac = 0.f;
#pragma unroll
            for (int n = 0; n < 8; ++n) {
                h[n]     = fmaf(__expf(dlt * A[n]),     h[n],     common * (float)b0[n]);
                h[n + 8] = fmaf(__expf(dlt * A[n + 8]), h[n + 8], common * (float)b1[n]);
                yac = fmaf(h[n], (float)c0[n], yac);
                yac = fmaf(h[n + 8], (float)c1[n], yac);
            }
            pool += yac + Dd * xv;
            bool gend = dir ? ((t & 3) == 0) : ((t & 3) == 3);
            if (gend) {
                yout[((size_t)b * TOK + (t >> 2)) * DD + d] = pool * 0.25f;
                pool = 0.f;
            }
        }
    }
}

// ---------------------------------------------------------------------------
// Final: out = zp*(silu(y1*mask)+silu(y2*mask)) + skip
// ---------------------------------------------------------------------------
__global__ __launch_bounds__(256) void final_kernel(
    const float* __restrict__ zp, const float* __restrict__ y1, const float* __restrict__ y2,
    const float* __restrict__ mask, const float* __restrict__ skipi, float* __restrict__ out)
{
    int p = blockIdx.x;
    int g = p & 1023;
    int d = threadIdx.x;
    size_t ip = (size_t)p * 256 + d;
    float mk = mask[g];
    float a1 = y1[ip] * mk, a2 = y2[ip] * mk;
    out[ip] = zp[ip] * (siluf(a1) + siluf(a2)) + skipi[ip];
}

// ---------------------------------------------------------------------------
extern "C" void kernel_launch(void* const* d_in, const int* in_sizes, int n_in,
                              void* d_out, int out_size, void* d_ws, size_t ws_size,
                              hipStream_t stream)
{
    const float* x      = (const float*)d_in[0];
    const float* ln_g   = (const float*)d_in[1];
    const float* ln_b   = (const float*)d_in[2];
    const float* W1     = (const float*)d_in[3];
    const float* b1     = (const float*)d_in[4];
    const float* W2     = (const float*)d_in[5];
    const float* b2     = (const float*)d_in[6];
    const float* Wcf    = (const float*)d_in[7];
    const float* bcf    = (const float*)d_in[8];
    const float* Wcb    = (const float*)d_in[9];
    const float* bcb    = (const float*)d_in[10];
    const float* Wdbc_f = (const float*)d_in[11];
    const float* Wdt_f  = (const float*)d_in[12];
    const float* bdt_f  = (const float*)d_in[13];
    const float* Alog_f = (const float*)d_in[14];
    const float* D_f    = (const float*)d_in[15];
    const float* Wdbc_b = (const float*)d_in[16];
    const float* Wdt_b  = (const float*)d_in[17];
    const float* bdt_b  = (const float*)d_in[18];
    const float* Alog_b = (const float*)d_in[19];
    const float* D_b    = (const float*)d_in[20];
    float* out = (float*)d_out;
    float* ws  = (float*)d_ws;

    __bf16* xnb = (__bf16*)(ws + O_XN);
    __bf16* dlf = (__bf16*)(ws + O_DLF);   // aliases xnb (dead after gemm1)
    __bf16* dlb = (__bf16*)(ws + O_DLB);
    __bf16* h1x = (__bf16*)(ws + O_H1X);
    __bf16* g2x = (__bf16*)(ws + O_G2X);
    __bf16* bmf = (__bf16*)(ws + O_BMF);
    __bf16* cmf = (__bf16*)(ws + O_CMF);
    __bf16* bmb = (__bf16*)(ws + O_BMB);
    __bf16* cmb = (__bf16*)(ws + O_CMB);
    float* zpb  = ws + O_ZP;
    float* skb  = ws + O_SKIP;
    float* y1b  = ws + O_Y1;
    float* y2b  = ws + O_Y2;
    __bf16* wf1 = (__bf16*)(ws + O_WF1);
    float* bf1  = ws + O_BF1;
    __bf16* wf2f = (__bf16*)(ws + O_WF2F);
    float* b2f  = ws + O_B2F;
    __bf16* wf2b = (__bf16*)(ws + O_WF2B);
    float* b2b  = ws + O_B2B;
    float* apr  = ws + O_APROD;
    float* hnd  = ws + O_HEND;   // hend, then hin in place
    float* mkb  = ws + O_MASK;

    prep_all_kernel<<<dim3(641, 2), 256, 0, stream>>>(
        W1, b1, W2, b2, Wcf, bcf, Wcb, bcb,
        Wdt_f, Wdbc_f, bdt_f, Wdt_b, Wdbc_b, bdt_b,
        wf1, bf1, wf2f, b2f, wf2b, b2b, mkb);
    ln_kernel<<<4096, 256, 0, stream>>>(x, ln_g, ln_b, xnb, skb);
    gemm1_mfma<<<dim3(128, 6), 256, 0, stream>>>(xnb, wf1, bf1, zpb, h1x, g2x);
    gemm2_mfma<<<dim3(128, 3, 2), 256, 0, stream>>>(h1x, g2x, wf2f, b2f, wf2b, b2b,
                                                    dlf, dlb, bmf, cmf, bmb, cmb);
    scan1_kernel<<<dim3(NCH, BB, 2), 256, 0, stream>>>(dlf, dlb, h1x, g2x, bmf, bmb,
                                                       Alog_f, Alog_b, apr, hnd);
    scan2_kernel<<<128, 256, 0, stream>>>(apr, hnd);
    scan3_kernel<<<dim3(NCH, BB, 2), 256, 0, stream>>>(dlf, dlb, h1x, g2x, bmf, bmb, cmf, cmb,
                                                       Alog_f, Alog_b, D_f, D_b, hnd, y1b, y2b);
    final_kernel<<<4096, 256, 0, stream>>>(zpb, y1b, y2b, mkb, skb, out);
}